// Round 8
// baseline (460.200 us; speedup 1.0000x reference)
//
#include <hip/hip_runtime.h>

#define LRELU 0.01f

// ---------------- problem constants ----------------
// relations: 0 follows U->U, 1 posts U->N, 2 posted_by N->U, 3 publishes S->N, 4 published_by N->S
static const int kNU = 50000, kNN = 20000, kNS = 2000;
static const int REL_E[5]  = {500000, 300000, 300000, 150000, 150000};
static const int REL_ND[5] = {50000, 20000, 50000, 20000, 2000};
// per-copy counter layout (8 copies of 284000, one per XCD)
static const int CNT_N = 284000;
static const int DOUT_OFF[5] = {0, 100000, 170000, 240000, 262000};
static const int DIN_OFF[5]  = {50000, 150000, 190000, 242000, 282000};
static const int XB_OFF[5]   = {0, 50000, 70000, 120000, 140000};
static const int RP_OFF[5]   = {0, 50001, 70002, 120003, 140004};
static const int CSR_OFF[5]  = {0, 500000, 800000, 1100000, 1250000};

using bf16x8 = __attribute__((ext_vector_type(8))) short;
using u16x8  = __attribute__((ext_vector_type(8))) unsigned short;
using f32x4  = __attribute__((ext_vector_type(4))) float;

__device__ __forceinline__ float bf2f(unsigned short u) {
  return __uint_as_float(((unsigned)u) << 16);
}
__device__ __forceinline__ unsigned short f2bf(float f) {  // RNE
  unsigned u = __float_as_uint(f);
  u += 0x7FFFu + ((u >> 16) & 1u);
  return (unsigned short)(u >> 16);
}

// ---------------- fused setup: build1 (XCD-local atomics) + wprep + f2bf ----------------
// 8 counter copies, one per XCD (selected via HW_REG_XCC_ID). Workgroup-scope
// atomics stay in the XCD's L2 (no memory-side round trip); copy c is only
// ever touched by XCD c, so cross-XCD lost updates are impossible by
// construction. pos stores (xcd<<28)|local_slot.

struct RelB1 { const int* src; const int* dst; int* pos; int doutoff; int dinoff; int E; };
struct PrepJob { const float* W0; const float* W128; unsigned short* hi;
                 unsigned short* lo; int NOUT; int lgK; int bstart; };
struct CvtJob { const float* in; unsigned short* out; int n4; int bstart; };
struct SetupArgs { RelB1 rel[5]; PrepJob pj[9]; CvtJob cj[3]; int* cnt; };

__global__ __launch_bounds__(256) void k_setup(SetupArgs a) {
  int bx = blockIdx.x;
  int t = threadIdx.x;
  if (bx < 5470) {
    constexpr int ESTART[6] = {0, 1954, 3126, 4298, 4884, 5470};
    int r = 0;
    while (bx >= ESTART[r + 1]) ++r;
    RelB1 e = a.rel[r];
    int i = (bx - ESTART[r]) * 256 + t;
    if (i < e.E) {
      unsigned xcc;
      asm volatile("s_getreg_b32 %0, hwreg(HW_REG_XCC_ID)" : "=s"(xcc));
      xcc &= 7u;
      int* base = a.cnt + (size_t)xcc * CNT_N;
      __hip_atomic_fetch_add(&base[e.doutoff + e.src[i]], 1,
                             __ATOMIC_RELAXED, __HIP_MEMORY_SCOPE_WORKGROUP);
      int p = __hip_atomic_fetch_add(&base[e.dinoff + e.dst[i]], 1,
                                     __ATOMIC_RELAXED, __HIP_MEMORY_SCOPE_WORKGROUP);
      e.pos[i] = p | (int)(xcc << 28);
    }
  } else if (bx < 6206) {
    int b = bx - 5470, ji = 0;
    while (ji < 8 && b >= a.pj[ji + 1].bstart) ++ji;
    PrepJob p = a.pj[ji];
    int idx = (b - p.bstart) * 256 + t;
    int K = 1 << p.lgK;
    int n = idx >> p.lgK, k = idx & (K - 1);
    if (n >= p.NOUT) return;
    float w = (k < 128) ? p.W0[k * p.NOUT + n] : p.W128[(k - 128) * p.NOUT + n];
    unsigned short h = f2bf(w);
    float res = w - bf2f(h);
    p.hi[n * K + k] = h;
    p.lo[n * K + k] = f2bf(res);
  } else {
    int b = bx - 6206, ji = 0;
    while (ji < 2 && b >= a.cj[ji + 1].bstart) ++ji;
    CvtJob p = a.cj[ji];
    int i = (b - p.bstart) * 256 + t;
    if (i >= p.n4) return;
    float4 v = ((const float4*)p.in)[i];
    ushort4 o = {f2bf(v.x), f2bf(v.y), f2bf(v.z), f2bf(v.w)};
    ((ushort4*)p.out)[i] = o;
  }
}

// ---------------- fused rs + xbase + scan1 (8-copy sums) ----------------

struct ScanArgs { const int* cnt[5]; int* rp[5]; int n[5]; int* csums; };
struct RsScanArgs { const int* cnt; float* rs; int* xbase; ScanArgs sa; };

__global__ __launch_bounds__(256) void k_rs_scan1(RsScanArgs a) {
  int bx = blockIdx.x;
  int t = threadIdx.x;
  if (bx < 1110) {
    int i = bx * 256 + t;
    if (i < CNT_N) {
      int v[8];
#pragma unroll
      for (int c = 0; c < 8; ++c) v[c] = a.cnt[(size_t)c * CNT_N + i];
      int run = 0;
#pragma unroll
      for (int c = 0; c < 8; ++c) { int tv = v[c]; v[c] = run; run += tv; }
      a.rs[i] = rsqrtf((float)(run > 1 ? run : 1));
      // if this is a din index, emit the 8-entry per-dst XCD base prefix
      int xbi = -1;
      if      (i >= 50000  && i < 100000) xbi = i - 50000;            // r0
      else if (i >= 150000 && i < 170000) xbi = 50000 + (i - 150000); // r1
      else if (i >= 190000 && i < 240000) xbi = 70000 + (i - 190000); // r2
      else if (i >= 242000 && i < 262000) xbi = 120000 + (i - 242000);// r3
      else if (i >= 282000)               xbi = 140000 + (i - 282000);// r4
      if (xbi >= 0) {
        int4 lo = {v[0], v[1], v[2], v[3]};
        int4 hi = {v[4], v[5], v[6], v[7]};
        ((int4*)&a.xbase[(size_t)xbi * 8])[0] = lo;
        ((int4*)&a.xbase[(size_t)xbi * 8])[1] = hi;
      }
    }
    return;
  }
  bx -= 1110;
  constexpr int CSTART[6] = {0, 49, 69, 118, 138, 140};
  int r = 0;
  while (bx >= CSTART[r + 1]) ++r;
  int chunk = bx - CSTART[r];
  int n = a.sa.n[r];
  int base = chunk * 1024;
  const int* cnt = a.sa.cnt[r];
  int s = 0;
#pragma unroll
  for (int j = 0; j < 4; ++j) {
    int idx = base + j * 256 + t;
    if (idx < n) {
#pragma unroll
      for (int c = 0; c < 8; ++c) s += cnt[(size_t)c * CNT_N + idx];
    }
  }
  __shared__ int sd[256];
  sd[t] = s;
  __syncthreads();
  for (int off = 128; off > 0; off >>= 1) {
    if (t < off) sd[t] += sd[t + off];
    __syncthreads();
  }
  if (t == 0) a.sa.csums[r * 64 + chunk] = sd[0];
}

// ---------------- scan3: local scan + in-block chunk-prefix ----------------

__global__ __launch_bounds__(256) void k_scan3(ScanArgs a) {
  constexpr int CSTART[6] = {0, 49, 69, 118, 138, 140};
  int bx = blockIdx.x, r = 0;
  while (bx >= CSTART[r + 1]) ++r;
  int chunk = bx - CSTART[r];
  int nch = CSTART[r + 1] - CSTART[r];
  int n = a.n[r];
  int base = chunk * 1024;
  const int* cnt = a.cnt[r];
  int* rp = a.rp[r];
  int t = threadIdx.x;
  int idx0 = base + t * 4;
  int v[4];
#pragma unroll
  for (int j = 0; j < 4; ++j) {
    int idx = idx0 + j, s = 0;
    if (idx < n) {
#pragma unroll
      for (int c = 0; c < 8; ++c) s += cnt[(size_t)c * CNT_N + idx];
    }
    v[j] = s;
  }
  int tsum = v[0] + v[1] + v[2] + v[3];
  __shared__ int sd[256];
  __shared__ int choff_sh;
  sd[t] = tsum;
  if (t < 64) {  // prefix of earlier chunk sums, wave reduce
    int cv = (t < chunk) ? a.csums[r * 64 + t] : 0;
    for (int o = 32; o > 0; o >>= 1) cv += __shfl_down(cv, o);
    if (t == 0) choff_sh = cv;
  }
  __syncthreads();
  for (int s = 1; s < 256; s <<= 1) {
    int add = (t >= s) ? sd[t - s] : 0;
    __syncthreads();
    sd[t] += add;
    __syncthreads();
  }
  int off = choff_sh + sd[t] - tsum;
#pragma unroll
  for (int j = 0; j < 4; ++j) {
    if (idx0 + j < n) rp[idx0 + j] = off;
    off += v[j];
  }
  if (chunk == nch - 1 && t == 255) rp[n] = choff_sh + sd[255];
}

// ---------------- build2: atomic-free CSR scatter (slot = rp + xbase + local) ----------------

struct RelB2 { const int* src; const int* dst; const int* rp; const int* pos;
               const int* xb; int* csr; int E; };
struct B2Args { RelB2 rel[5]; };

__global__ __launch_bounds__(256) void k_build2(B2Args a) {
  constexpr int ESTART[6] = {0, 1954, 3126, 4298, 4884, 5470};
  int bx = blockIdx.x, r = 0;
  while (bx >= ESTART[r + 1]) ++r;
  RelB2 f = a.rel[r];
  int i = (bx - ESTART[r]) * 256 + threadIdx.x;
  if (i < f.E) {
    int pc = f.pos[i];
    int c = ((unsigned)pc) >> 28;
    int lp = pc & 0x0FFFFFFF;
    int d = f.dst[i];
    f.csr[f.rp[d] + f.xb[(size_t)d * 8 + c] + lp] = f.src[i];
  }
}

// ---------------- gather: 16 lanes/row, 16-edge batches, shfl-broadcast ----------------

struct RelG {
  const int* rp; const int* csr; const unsigned short* xb;
  const float* rso; const float* rsi;
  unsigned short* out; int stride; int ooff; int nd;
};
struct GArgs { RelG rel[5]; };

#define GROW(vv, cc)                                                              \
  _Pragma("unroll") for (int q = 0; q < 8; ++q)                                   \
      acc[q] = fmaf(__uint_as_float(((unsigned)(unsigned short)vv[q]) << 16), cc, acc[q]);

__global__ __launch_bounds__(256) void k_gather(GArgs a) {
  constexpr int GSTART[6] = {0, 3125, 4375, 7500, 8750, 8875};
  int bx = blockIdx.x, r = 0;
  while (bx >= GSTART[r + 1]) ++r;
  RelG g = a.rel[r];
  int t = threadIdx.x;
  int sub = t & 15;
  int wid = (bx - GSTART[r]) * 16 + (t >> 4);
  if (wid >= g.nd) return;
  int e0 = g.rp[wid], e1 = g.rp[wid + 1];
  const unsigned short* xb = g.xb;
  float acc[8] = {};
  for (int base = e0; base < e1; base += 16) {
    int m = e1 - base;
    if (m > 16) m = 16;
    int ei = base + (sub < m ? sub : 0);
    int se = g.csr[ei];       // 16 edges loaded in parallel (coalesced)
    float sc = g.rso[se];     // 16 scale gathers in parallel
    int j = 0;
    for (; j + 8 <= m; j += 8) {
      int s0 = __shfl(se, j, 16), s1 = __shfl(se, j + 1, 16);
      int s2 = __shfl(se, j + 2, 16), s3 = __shfl(se, j + 3, 16);
      int s4 = __shfl(se, j + 4, 16), s5 = __shfl(se, j + 5, 16);
      int s6 = __shfl(se, j + 6, 16), s7 = __shfl(se, j + 7, 16);
      float c0 = __shfl(sc, j, 16), c1 = __shfl(sc, j + 1, 16);
      float c2 = __shfl(sc, j + 2, 16), c3 = __shfl(sc, j + 3, 16);
      float c4 = __shfl(sc, j + 4, 16), c5 = __shfl(sc, j + 5, 16);
      float c6 = __shfl(sc, j + 6, 16), c7 = __shfl(sc, j + 7, 16);
      bf16x8 v0 = *(const bf16x8*)&xb[(size_t)s0 * 128 + sub * 8];
      bf16x8 v1 = *(const bf16x8*)&xb[(size_t)s1 * 128 + sub * 8];
      bf16x8 v2 = *(const bf16x8*)&xb[(size_t)s2 * 128 + sub * 8];
      bf16x8 v3 = *(const bf16x8*)&xb[(size_t)s3 * 128 + sub * 8];
      bf16x8 v4 = *(const bf16x8*)&xb[(size_t)s4 * 128 + sub * 8];
      bf16x8 v5 = *(const bf16x8*)&xb[(size_t)s5 * 128 + sub * 8];
      bf16x8 v6 = *(const bf16x8*)&xb[(size_t)s6 * 128 + sub * 8];
      bf16x8 v7 = *(const bf16x8*)&xb[(size_t)s7 * 128 + sub * 8];
      GROW(v0, c0) GROW(v1, c1) GROW(v2, c2) GROW(v3, c3)
      GROW(v4, c4) GROW(v5, c5) GROW(v6, c6) GROW(v7, c7)
    }
    for (; j < m; ++j) {
      int s0 = __shfl(se, j, 16);
      float c0 = __shfl(sc, j, 16);
      bf16x8 v0 = *(const bf16x8*)&xb[(size_t)s0 * 128 + sub * 8];
      GROW(v0, c0)
    }
  }
  float si = g.rsi[wid];
  u16x8 o;
#pragma unroll
  for (int q = 0; q < 8; ++q) o[q] = f2bf(acc[q] * si);
  *(u16x8*)&g.out[(size_t)wid * g.stride + g.ooff + sub * 8] = o;
}

// ---------------- MFMA GEMM (fused 3 dst-types per launch) ----------------

struct MJob { const unsigned short* A; const unsigned short* Wh; const unsigned short* Wl;
              const float* b0; const float* b1; float scale; int lrelu;
              float* H; int ldh; unsigned short* Hb; int M; int bstart; };
struct MArgs { MJob j[3]; };

template <int KCH, int NW>
__device__ __forceinline__ void mgemm_body(const MJob& p, int bxl) {
  constexpr int KP = KCH * 128;
  int t = threadIdx.x;
  int w = t >> 6, l = t & 63;
  int lo16 = l & 15, hi4 = l >> 4;
  int m0 = bxl * 64;
  int M = p.M;
  const unsigned short* A = p.A;
  f32x4 acc[4][NW] = {};
  for (int s = 0; s < KP / 32; ++s) {
    int kbase = s * 32 + hi4 * 8;
    bf16x8 af[4];
#pragma unroll
    for (int mf = 0; mf < 4; ++mf) {
      int row = m0 + mf * 16 + lo16;
      row = row < M ? row : M - 1;  // clamp; OOB rows never stored
      af[mf] = *(const bf16x8*)&A[(size_t)row * KP + kbase];
    }
#pragma unroll
    for (int nf = 0; nf < NW; ++nf) {
      int n = (w * NW + nf) * 16 + lo16;
      bf16x8 bh = *(const bf16x8*)&p.Wh[(size_t)n * KP + kbase];
      bf16x8 bl = *(const bf16x8*)&p.Wl[(size_t)n * KP + kbase];
#pragma unroll
      for (int mf = 0; mf < 4; ++mf) {
        acc[mf][nf] = __builtin_amdgcn_mfma_f32_16x16x32_bf16(af[mf], bh, acc[mf][nf], 0, 0, 0);
        acc[mf][nf] = __builtin_amdgcn_mfma_f32_16x16x32_bf16(af[mf], bl, acc[mf][nf], 0, 0, 0);
      }
    }
  }
#pragma unroll
  for (int nf = 0; nf < NW; ++nf) {
    int col = (w * NW + nf) * 16 + lo16;
    float bs = p.b0[col];
    if (p.b1) bs += p.b1[col];
#pragma unroll
    for (int mf = 0; mf < 4; ++mf) {
#pragma unroll
      for (int rr = 0; rr < 4; ++rr) {
        int row = m0 + mf * 16 + hi4 * 4 + rr;
        if (row < M) {
          float o = p.scale * (acc[mf][nf][rr] + bs);
          if (p.lrelu) o = o >= 0.f ? o : LRELU * o;
          if (p.H) p.H[(size_t)row * p.ldh + col] = o;
          if (p.Hb) p.Hb[(size_t)row * p.ldh + col] = f2bf(o);
        }
      }
    }
  }
}

__global__ __launch_bounds__(256) void k_mgemm3(MArgs a) {
  int bx = blockIdx.x;
  if (bx < a.j[1].bstart)      mgemm_body<2, 2>(a.j[0], bx);
  else if (bx < a.j[2].bstart) mgemm_body<2, 2>(a.j[1], bx - a.j[1].bstart);
  else                         mgemm_body<1, 2>(a.j[2], bx - a.j[2].bstart);
}

__global__ __launch_bounds__(256) void k_proj3(MArgs a) {
  int bx = blockIdx.x;
  if (bx < a.j[1].bstart)      mgemm_body<1, 1>(a.j[0], bx);
  else if (bx < a.j[2].bstart) mgemm_body<1, 1>(a.j[1], bx - a.j[1].bstart);
  else                         mgemm_body<1, 1>(a.j[2], bx - a.j[2].bstart);
}

// ---------------- host ----------------

extern "C" void kernel_launch(void* const* d_in, const int* in_sizes, int n_in,
                              void* d_out, int out_size, void* d_ws, size_t ws_size,
                              hipStream_t stream) {
  const float* xu = (const float*)d_in[0];
  const float* xn = (const float*)d_in[1];
  const float* xs = (const float*)d_in[2];
  const float* W1 = (const float*)d_in[3];
  const float* b1 = (const float*)d_in[4];
  const float* W2 = (const float*)d_in[5];
  const float* b2 = (const float*)d_in[6];
  const float* Wu = (const float*)d_in[7];
  const float* bu = (const float*)d_in[8];
  const float* Wn = (const float*)d_in[9];
  const float* bn = (const float*)d_in[10];
  const float* Wsrc = (const float*)d_in[11];
  const float* bsrc = (const float*)d_in[12];
  const int* SRC[5] = {(const int*)d_in[13], (const int*)d_in[15], (const int*)d_in[17],
                       (const int*)d_in[19], (const int*)d_in[21]};
  const int* DST[5] = {(const int*)d_in[14], (const int*)d_in[16], (const int*)d_in[18],
                       (const int*)d_in[20], (const int*)d_in[22]};

  // ---- workspace layout (~68.4 MB; counters + xbase live in d_out scratch) ----
  int* ws_i = (int*)d_ws;
  int* rp = ws_i;                           // 142008
  int* csr = ws_i + 142008;                 // 1400000
  int* pos = ws_i + 1542008;                // 1400000
  int* csums = ws_i + 2942008;              // 320
  float* rs = (float*)(ws_i + 2942328);     // 284000
  unsigned short* wt = (unsigned short*)(rs + 284000);    // 376832
  unsigned short* aggU = wt + 376832;       // 50000*256
  unsigned short* aggN = aggU + 12800000;   // 20000*256
  unsigned short* aggS = aggN + 5120000;    // 2000*128
  unsigned short* xbU = aggS + 256000;      // 50000*128
  unsigned short* xbN = xbU + 6400000;      // 20000*128
  unsigned short* xbS = xbN + 2560000;      // 2000*128

  // wt sub-offsets (hi, lo consecutive per job)
  unsigned short* L1U_h = wt, * L1U_l = wt + 32768;
  unsigned short* L1N_h = wt + 65536, * L1N_l = wt + 98304;
  unsigned short* L1S_h = wt + 131072, * L1S_l = wt + 147456;
  unsigned short* L2U_h = wt + 163840, * L2U_l = wt + 196608;
  unsigned short* L2N_h = wt + 229376, * L2N_l = wt + 262144;
  unsigned short* L2S_h = wt + 294912, * L2S_l = wt + 311296;
  unsigned short* PU_h = wt + 327680, * PU_l = wt + 335872;
  unsigned short* PN_h = wt + 344064, * PN_l = wt + 352256;
  unsigned short* PS_h = wt + 360448, * PS_l = wt + 368640;

  // ---- d_out layout ----
  float* outf = (float*)d_out;
  float* ou = outf;                 // 50000*64
  float* on = outf + 3200000;       // 20000*64
  float* osrc = outf + 4480000;     // 2000*64
  float* hu = outf + 4608000;       // 50000*128
  float* hn = outf + 11008000;      // 20000*128
  float* hs = outf + 13568000;      // 2000*128

  // 8 XCD-local counter copies (284000 each) in hu's slot: 9.09 MB < 25.6 MB.
  // xbase (142000 dsts x 8 XCD prefixes) in hn's slot: 4.54 MB < 10.24 MB.
  // Both dead once layer-2 mgemm3 overwrites hu/hn (after build2).
  int* cnt = (int*)hu;
  int* xbase = (int*)hn;

  // ---- fused setup: graph count + weight prep + feature convert ----
  hipMemsetAsync(cnt, 0, (size_t)CNT_N * 8 * 4, stream);
  SetupArgs su;
  for (int r = 0; r < 5; ++r)
    su.rel[r] = {SRC[r], DST[r], pos + CSR_OFF[r], DOUT_OFF[r], DIN_OFF[r], REL_E[r]};
  su.cnt = cnt;
  su.pj[0] = {W1, W1 + 2 * 16384, L1U_h, L1U_l, 128, 8, 0};
  su.pj[1] = {W1 + 16384, W1 + 3 * 16384, L1N_h, L1N_l, 128, 8, 128};
  su.pj[2] = {W1 + 4 * 16384, nullptr, L1S_h, L1S_l, 128, 7, 256};
  su.pj[3] = {W2, W2 + 2 * 16384, L2U_h, L2U_l, 128, 8, 320};
  su.pj[4] = {W2 + 16384, W2 + 3 * 16384, L2N_h, L2N_l, 128, 8, 448};
  su.pj[5] = {W2 + 4 * 16384, nullptr, L2S_h, L2S_l, 128, 7, 576};
  su.pj[6] = {Wu, nullptr, PU_h, PU_l, 64, 7, 640};
  su.pj[7] = {Wn, nullptr, PN_h, PN_l, 64, 7, 672};
  su.pj[8] = {Wsrc, nullptr, PS_h, PS_l, 64, 7, 704};
  su.cj[0] = {xu, xbU, kNU * 32, 0};
  su.cj[1] = {xn, xbN, kNN * 32, 6250};
  su.cj[2] = {xs, xbS, kNS * 32, 8750};
  k_setup<<<15206, 256, 0, stream>>>(su);

  // ---- rs + xbase + scan ----
  ScanArgs sa;
  for (int r = 0; r < 5; ++r) {
    sa.cnt[r] = cnt + DIN_OFF[r];     // copy-0 base; kernels add c*CNT_N
    sa.rp[r] = rp + RP_OFF[r];
    sa.n[r] = REL_ND[r];
  }
  sa.csums = csums;
  RsScanArgs rsa;
  rsa.cnt = cnt;
  rsa.rs = rs;
  rsa.xbase = xbase;
  rsa.sa = sa;
  k_rs_scan1<<<1250, 256, 0, stream>>>(rsa);
  k_scan3<<<140, 256, 0, stream>>>(sa);

  B2Args b2a;
  for (int r = 0; r < 5; ++r)
    b2a.rel[r] = {SRC[r], DST[r], rp + RP_OFF[r], pos + CSR_OFF[r],
                  xbase + (size_t)XB_OFF[r] * 8, csr + CSR_OFF[r], REL_E[r]};
  k_build2<<<5470, 256, 0, stream>>>(b2a);

  // ---- hetero layers: gather + fused MFMA GEMM ----
  auto layer = [&](const unsigned short* Uh, const unsigned short* Ul,
                   const unsigned short* Nh, const unsigned short* Nl,
                   const unsigned short* Sh, const unsigned short* Sl,
                   const float* bl, bool last) {
    const unsigned short* XIN[5] = {xbU, xbU, xbN, xbS, xbN};
    unsigned short* OUT[5] = {aggU, aggN, aggU, aggN, aggS};
    const int OSTR[5] = {256, 256, 256, 256, 128};
    const int OOFF[5] = {0, 0, 128, 128, 0};
    GArgs ga;
    for (int r = 0; r < 5; ++r)
      ga.rel[r] = {rp + RP_OFF[r], csr + CSR_OFF[r], XIN[r], rs + DOUT_OFF[r],
                   rs + DIN_OFF[r], OUT[r], OSTR[r], OOFF[r], REL_ND[r]};
    k_gather<<<8875, 256, 0, stream>>>(ga);
    MArgs ma;
    // layer-1 f32 H is dead (layer-2 consumes the bf16 copy) -> H=nullptr
    ma.j[0] = {aggU, Uh, Ul, bl, bl + 2 * 128, 0.5f, 1,
               last ? hu : nullptr, 128, xbU, kNU, 0};
    ma.j[1] = {aggN, Nh, Nl, bl + 128, bl + 3 * 128, 0.5f, 1,
               last ? hn : nullptr, 128, xbN, kNN, 782};
    ma.j[2] = {aggS, Sh, Sl, bl + 4 * 128, nullptr, 1.0f, 1,
               last ? hs : nullptr, 128, xbS, kNS, 1095};
    k_mgemm3<<<1127, 256, 0, stream>>>(ma);
  };

  layer(L1U_h, L1U_l, L1N_h, L1N_l, L1S_h, L1S_l, b1, false);  // x -> h1 (bf16 only)
  layer(L2U_h, L2U_l, L2N_h, L2N_l, L2S_h, L2S_l, b2, true);   // h1 -> h2 (f32 + bf16)

  // ---- output projections (read bf16 h2 from xb*) ----
  MArgs pm;
  pm.j[0] = {xbU, PU_h, PU_l, bu, nullptr, 1.0f, 0, ou, 64, nullptr, kNU, 0};
  pm.j[1] = {xbN, PN_h, PN_l, bn, nullptr, 1.0f, 0, on, 64, nullptr, kNN, 782};
  pm.j[2] = {xbS, PS_h, PS_l, bsrc, nullptr, 1.0f, 0, osrc, 64, nullptr, kNS, 1095};
  k_proj3<<<1127, 256, 0, stream>>>(pm);
}

// Round 9
// 384.415 us; speedup vs baseline: 1.1971x; 1.1971x over previous
//
#include <hip/hip_runtime.h>

#define LRELU 0.01f

// ---------------- problem constants ----------------
// relations: 0 follows U->U, 1 posts U->N, 2 posted_by N->U, 3 publishes S->N, 4 published_by N->S
static const int kNU = 50000, kNN = 20000, kNS = 2000;
static const int REL_E[5]  = {500000, 300000, 300000, 150000, 150000};
static const int REL_ND[5] = {50000, 20000, 50000, 20000, 2000};
static const int DOUT_OFF[5] = {0, 100000, 170000, 240000, 262000};
static const int DIN_OFF[5]  = {50000, 150000, 190000, 242000, 282000};
static const int RP_OFF[5]   = {0, 50001, 70002, 120003, 140004};
static const int CSR_OFF[5]  = {0, 500000, 800000, 1100000, 1250000};

using bf16x8 = __attribute__((ext_vector_type(8))) short;
using u16x8  = __attribute__((ext_vector_type(8))) unsigned short;
using f32x4  = __attribute__((ext_vector_type(4))) float;

__device__ __forceinline__ float bf2f(unsigned short u) {
  return __uint_as_float(((unsigned)u) << 16);
}
__device__ __forceinline__ unsigned short f2bf(float f) {  // RNE
  unsigned u = __float_as_uint(f);
  u += 0x7FFFu + ((u >> 16) & 1u);
  return (unsigned short)(u >> 16);
}

// ---------------- fused setup ----------------
// Roles, striped (a,a,o) so non-atomic work is co-resident with the
// atomic-rate-bound phase (TCC atomic ceiling ~19G/s leaves VALU/MFMA idle):
//   role 0 (5470 blocks): edge counting, single-copy device atomics
//   role 1a (2222 blocks): layer-1 transform GEMM Y_r = bf16(x) @ (W1_r hi+lo)
//   role 1b (416 blocks):  layer-2/proj weight transpose + hi/lo split

struct RelB1 { const int* src; const int* dst; int* pos; int doutoff; int dinoff; int E; };
struct TJob  { const float* X; const float* W; unsigned short* Y; int M; };
struct PrepJob { const float* W0; const float* W128; unsigned short* hi;
                 unsigned short* lo; int NOUT; int lgK; int bstart; };
struct SetupArgs { RelB1 rel[5]; TJob tj[5]; PrepJob pj[6]; int* cnt; };

__device__ __forceinline__ void transform_body(const TJob& p, int bxl, int t) {
  int w = t >> 6, l = t & 63;
  int lo16 = l & 15, hi4 = l >> 4;
  int m0 = bxl * 64;
  int M = p.M;
  f32x4 acc[4][2] = {};
  for (int s = 0; s < 4; ++s) {  // K = 128, 32 per step
    int kbase = s * 32 + hi4 * 8;
    bf16x8 af[4];
#pragma unroll
    for (int mf = 0; mf < 4; ++mf) {
      int row = m0 + mf * 16 + lo16;
      row = row < M ? row : M - 1;  // clamp; OOB rows never stored
      const float* xr = &p.X[(size_t)row * 128 + kbase];
      float4 xa = *(const float4*)xr;
      float4 xb = *(const float4*)(xr + 4);
      af[mf][0] = (short)f2bf(xa.x); af[mf][1] = (short)f2bf(xa.y);
      af[mf][2] = (short)f2bf(xa.z); af[mf][3] = (short)f2bf(xa.w);
      af[mf][4] = (short)f2bf(xb.x); af[mf][5] = (short)f2bf(xb.y);
      af[mf][6] = (short)f2bf(xb.z); af[mf][7] = (short)f2bf(xb.w);
    }
#pragma unroll
    for (int nf = 0; nf < 2; ++nf) {
      int n = (w * 2 + nf) * 16 + lo16;
      bf16x8 bh, bl;
#pragma unroll
      for (int j = 0; j < 8; ++j) {
        float wv = p.W[(size_t)(kbase + j) * 128 + n];
        unsigned short h = f2bf(wv);
        bh[j] = (short)h;
        bl[j] = (short)f2bf(wv - bf2f(h));
      }
#pragma unroll
      for (int mf = 0; mf < 4; ++mf) {
        acc[mf][nf] = __builtin_amdgcn_mfma_f32_16x16x32_bf16(af[mf], bh, acc[mf][nf], 0, 0, 0);
        acc[mf][nf] = __builtin_amdgcn_mfma_f32_16x16x32_bf16(af[mf], bl, acc[mf][nf], 0, 0, 0);
      }
    }
  }
#pragma unroll
  for (int nf = 0; nf < 2; ++nf) {
    int col = (w * 2 + nf) * 16 + lo16;
#pragma unroll
    for (int mf = 0; mf < 4; ++mf) {
#pragma unroll
      for (int rr = 0; rr < 4; ++rr) {
        int row = m0 + mf * 16 + hi4 * 4 + rr;
        if (row < M) p.Y[(size_t)row * 128 + col] = f2bf(acc[mf][nf][rr]);
      }
    }
  }
}

__global__ __launch_bounds__(256) void k_setup(SetupArgs a) {
  int bx = blockIdx.x;
  int t = threadIdx.x;
  int role, idx;
  if (bx < 7914) {  // stripes of (atomic, atomic, other); 2638 other blocks
    int g = bx / 3, m = bx - g * 3;
    if (m < 2) { role = 0; idx = g * 2 + m; }
    else       { role = 1; idx = g; }
  } else {          // remaining atomic blocks
    role = 0; idx = 5276 + (bx - 7914);
  }
  if (role == 0) {
    constexpr int ESTART[6] = {0, 1954, 3126, 4298, 4884, 5470};
    int r = 0;
    while (idx >= ESTART[r + 1]) ++r;
    RelB1 e = a.rel[r];
    int i = (idx - ESTART[r]) * 256 + t;
    if (i < e.E) {
      atomicAdd(a.cnt + e.doutoff + e.src[i], 1);
      e.pos[i] = atomicAdd(a.cnt + e.dinoff + e.dst[i], 1);
    }
  } else if (idx < 2222) {
    constexpr int TSTART[6] = {0, 782, 1564, 1877, 1909, 2222};
    int r = 0;
    while (idx >= TSTART[r + 1]) ++r;
    transform_body(a.tj[r], idx - TSTART[r], t);
  } else {
    int b = idx - 2222, ji = 0;
    while (ji < 5 && b >= a.pj[ji + 1].bstart) ++ji;
    PrepJob p = a.pj[ji];
    int eidx = (b - p.bstart) * 256 + t;
    int K = 1 << p.lgK;
    int n = eidx >> p.lgK, k = eidx & (K - 1);
    if (n >= p.NOUT) return;
    float w = (k < 128) ? p.W0[k * p.NOUT + n] : p.W128[(k - 128) * p.NOUT + n];
    unsigned short h = f2bf(w);
    float res = w - bf2f(h);
    p.hi[n * K + k] = h;
    p.lo[n * K + k] = f2bf(res);
  }
}

// ---------------- fused rs + scan1 ----------------

struct ScanArgs { const int* cnt[5]; int* rp[5]; int n[5]; int* csums; };
struct RsScanArgs { const int* cnt; float* rs; ScanArgs sa; };

__global__ __launch_bounds__(256) void k_rs_scan1(RsScanArgs a) {
  int bx = blockIdx.x;
  int t = threadIdx.x;
  if (bx < 1110) {
    int i = bx * 256 + t;
    if (i < 284000) {
      int c = a.cnt[i];
      a.rs[i] = rsqrtf((float)(c > 1 ? c : 1));
    }
    return;
  }
  bx -= 1110;
  constexpr int CSTART[6] = {0, 49, 69, 118, 138, 140};
  int r = 0;
  while (bx >= CSTART[r + 1]) ++r;
  int chunk = bx - CSTART[r];
  int n = a.sa.n[r];
  int base = chunk * 1024;
  const int* cnt = a.sa.cnt[r];
  int s = 0;
#pragma unroll
  for (int j = 0; j < 4; ++j) {
    int idx = base + j * 256 + t;
    if (idx < n) s += cnt[idx];
  }
  __shared__ int sd[256];
  sd[t] = s;
  __syncthreads();
  for (int off = 128; off > 0; off >>= 1) {
    if (t < off) sd[t] += sd[t + off];
    __syncthreads();
  }
  if (t == 0) a.sa.csums[r * 64 + chunk] = sd[0];
}

// ---------------- scan3: local scan + in-block chunk-prefix ----------------

__global__ __launch_bounds__(256) void k_scan3(ScanArgs a) {
  constexpr int CSTART[6] = {0, 49, 69, 118, 138, 140};
  int bx = blockIdx.x, r = 0;
  while (bx >= CSTART[r + 1]) ++r;
  int chunk = bx - CSTART[r];
  int nch = CSTART[r + 1] - CSTART[r];
  int n = a.n[r];
  int base = chunk * 1024;
  const int* cnt = a.cnt[r];
  int* rp = a.rp[r];
  int t = threadIdx.x;
  int idx0 = base + t * 4;
  int v[4];
#pragma unroll
  for (int j = 0; j < 4; ++j) v[j] = (idx0 + j < n) ? cnt[idx0 + j] : 0;
  int tsum = v[0] + v[1] + v[2] + v[3];
  __shared__ int sd[256];
  __shared__ int choff_sh;
  sd[t] = tsum;
  if (t < 64) {  // prefix of earlier chunk sums, wave reduce
    int cv = (t < chunk) ? a.csums[r * 64 + t] : 0;
    for (int o = 32; o > 0; o >>= 1) cv += __shfl_down(cv, o);
    if (t == 0) choff_sh = cv;
  }
  __syncthreads();
  for (int s = 1; s < 256; s <<= 1) {
    int add = (t >= s) ? sd[t - s] : 0;
    __syncthreads();
    sd[t] += add;
    __syncthreads();
  }
  int off = choff_sh + sd[t] - tsum;
#pragma unroll
  for (int j = 0; j < 4; ++j) {
    if (idx0 + j < n) rp[idx0 + j] = off;
    off += v[j];
  }
  if (chunk == nch - 1 && t == 255) rp[n] = choff_sh + sd[255];
}

// ---------------- build2: atomic-free CSR scatter ----------------

struct RelB2 { const int* src; const int* dst; const int* rp; const int* pos; int* csr; int E; };
struct B2Args { RelB2 rel[5]; };

__global__ __launch_bounds__(256) void k_build2(B2Args a) {
  constexpr int ESTART[6] = {0, 1954, 3126, 4298, 4884, 5470};
  int bx = blockIdx.x, r = 0;
  while (bx >= ESTART[r + 1]) ++r;
  RelB2 f = a.rel[r];
  int i = (bx - ESTART[r]) * 256 + threadIdx.x;
  if (i < f.E) {
    int d = f.dst[i];
    f.csr[f.rp[d] + f.pos[i]] = f.src[i];
  }
}

// ---------------- shared gather inner loop ----------------
// 16 lanes per dst row; 16-edge batches: coalesced csr read + parallel rso
// gathers, then width-16 shfl broadcast with 8 row-loads in flight.

#define GROW(vv, cc)                                                              \
  _Pragma("unroll") for (int q = 0; q < 8; ++q)                                   \
      acc[q] = fmaf(__uint_as_float(((unsigned)(unsigned short)vv[q]) << 16), cc, acc[q]);

__device__ __forceinline__ void gat_accum(const int* __restrict__ rp,
    const int* __restrict__ csr, const unsigned short* __restrict__ Y,
    const float* __restrict__ rso, int wid, int sub, float* acc) {
  int e0 = rp[wid], e1 = rp[wid + 1];
  for (int base = e0; base < e1; base += 16) {
    int m = e1 - base;
    if (m > 16) m = 16;
    int ei = base + (sub < m ? sub : 0);
    int se = csr[ei];
    float sc = rso[se];
    int j = 0;
    for (; j + 8 <= m; j += 8) {
      int s0 = __shfl(se, j, 16), s1 = __shfl(se, j + 1, 16);
      int s2 = __shfl(se, j + 2, 16), s3 = __shfl(se, j + 3, 16);
      int s4 = __shfl(se, j + 4, 16), s5 = __shfl(se, j + 5, 16);
      int s6 = __shfl(se, j + 6, 16), s7 = __shfl(se, j + 7, 16);
      float c0 = __shfl(sc, j, 16), c1 = __shfl(sc, j + 1, 16);
      float c2 = __shfl(sc, j + 2, 16), c3 = __shfl(sc, j + 3, 16);
      float c4 = __shfl(sc, j + 4, 16), c5 = __shfl(sc, j + 5, 16);
      float c6 = __shfl(sc, j + 6, 16), c7 = __shfl(sc, j + 7, 16);
      bf16x8 v0 = *(const bf16x8*)&Y[(size_t)s0 * 128 + sub * 8];
      bf16x8 v1 = *(const bf16x8*)&Y[(size_t)s1 * 128 + sub * 8];
      bf16x8 v2 = *(const bf16x8*)&Y[(size_t)s2 * 128 + sub * 8];
      bf16x8 v3 = *(const bf16x8*)&Y[(size_t)s3 * 128 + sub * 8];
      bf16x8 v4 = *(const bf16x8*)&Y[(size_t)s4 * 128 + sub * 8];
      bf16x8 v5 = *(const bf16x8*)&Y[(size_t)s5 * 128 + sub * 8];
      bf16x8 v6 = *(const bf16x8*)&Y[(size_t)s6 * 128 + sub * 8];
      bf16x8 v7 = *(const bf16x8*)&Y[(size_t)s7 * 128 + sub * 8];
      GROW(v0, c0) GROW(v1, c1) GROW(v2, c2) GROW(v3, c3)
      GROW(v4, c4) GROW(v5, c5) GROW(v6, c6) GROW(v7, c7)
    }
    for (; j < m; ++j) {
      int s0 = __shfl(se, j, 16);
      float c0 = __shfl(sc, j, 16);
      bf16x8 v0 = *(const bf16x8*)&Y[(size_t)s0 * 128 + sub * 8];
      GROW(v0, c0)
    }
  }
}

// ---------------- layer-1 gather: Y -> h1 (bias + mean + lrelu fused) ----------------

struct G1Rel { const int* rp; const int* csr; const unsigned short* Y;
               const float* rso; const float* rsi; };
struct G1Args { G1Rel rel[5]; const float* b;
                unsigned short* hU; unsigned short* hN; unsigned short* hS; };

__global__ __launch_bounds__(256) void k_gather1(G1Args a) {
  int bx = blockIdx.x;
  int t = threadIdx.x;
  int sub = t & 15;
  float acc[8], tot[8];
#pragma unroll
  for (int q = 0; q < 8; ++q) acc[q] = 0.f;
  if (bx < 3125) {  // users: rel 0 + rel 2
    int wid = bx * 16 + (t >> 4);
    gat_accum(a.rel[0].rp, a.rel[0].csr, a.rel[0].Y, a.rel[0].rso, wid, sub, acc);
    float s0 = a.rel[0].rsi[wid];
#pragma unroll
    for (int q = 0; q < 8; ++q) { tot[q] = s0 * acc[q]; acc[q] = 0.f; }
    gat_accum(a.rel[2].rp, a.rel[2].csr, a.rel[2].Y, a.rel[2].rso, wid, sub, acc);
    float s2 = a.rel[2].rsi[wid];
    const float* b0 = a.b;
    const float* b2 = a.b + 2 * 128;
    u16x8 o;
#pragma unroll
    for (int q = 0; q < 8; ++q) {
      float v = 0.5f * (tot[q] + s2 * acc[q] + b0[sub * 8 + q] + b2[sub * 8 + q]);
      v = v >= 0.f ? v : LRELU * v;
      o[q] = f2bf(v);
    }
    *(u16x8*)&a.hU[(size_t)wid * 128 + sub * 8] = o;
  } else if (bx < 4375) {  // news: rel 1 + rel 3
    int wid = (bx - 3125) * 16 + (t >> 4);
    gat_accum(a.rel[1].rp, a.rel[1].csr, a.rel[1].Y, a.rel[1].rso, wid, sub, acc);
    float s1 = a.rel[1].rsi[wid];
#pragma unroll
    for (int q = 0; q < 8; ++q) { tot[q] = s1 * acc[q]; acc[q] = 0.f; }
    gat_accum(a.rel[3].rp, a.rel[3].csr, a.rel[3].Y, a.rel[3].rso, wid, sub, acc);
    float s3 = a.rel[3].rsi[wid];
    const float* b1v = a.b + 128;
    const float* b3 = a.b + 3 * 128;
    u16x8 o;
#pragma unroll
    for (int q = 0; q < 8; ++q) {
      float v = 0.5f * (tot[q] + s3 * acc[q] + b1v[sub * 8 + q] + b3[sub * 8 + q]);
      v = v >= 0.f ? v : LRELU * v;
      o[q] = f2bf(v);
    }
    *(u16x8*)&a.hN[(size_t)wid * 128 + sub * 8] = o;
  } else {  // sources: rel 4
    int wid = (bx - 4375) * 16 + (t >> 4);
    gat_accum(a.rel[4].rp, a.rel[4].csr, a.rel[4].Y, a.rel[4].rso, wid, sub, acc);
    float s4 = a.rel[4].rsi[wid];
    const float* b4 = a.b + 4 * 128;
    u16x8 o;
#pragma unroll
    for (int q = 0; q < 8; ++q) {
      float v = s4 * acc[q] + b4[sub * 8 + q];
      v = v >= 0.f ? v : LRELU * v;
      o[q] = f2bf(v);
    }
    *(u16x8*)&a.hS[(size_t)wid * 128 + sub * 8] = o;
  }
}

// ---------------- layer-2 gather (h1 -> agg, bf16) ----------------

struct RelG {
  const int* rp; const int* csr; const unsigned short* xb;
  const float* rso; const float* rsi;
  unsigned short* out; int stride; int ooff; int nd;
};
struct GArgs { RelG rel[5]; };

__global__ __launch_bounds__(256) void k_gather(GArgs a) {
  constexpr int GSTART[6] = {0, 3125, 4375, 7500, 8750, 8875};
  int bx = blockIdx.x, r = 0;
  while (bx >= GSTART[r + 1]) ++r;
  RelG g = a.rel[r];
  int t = threadIdx.x;
  int sub = t & 15;
  int wid = (bx - GSTART[r]) * 16 + (t >> 4);
  if (wid >= g.nd) return;
  float acc[8];
#pragma unroll
  for (int q = 0; q < 8; ++q) acc[q] = 0.f;
  gat_accum(g.rp, g.csr, g.xb, g.rso, wid, sub, acc);
  float si = g.rsi[wid];
  u16x8 o;
#pragma unroll
  for (int q = 0; q < 8; ++q) o[q] = f2bf(acc[q] * si);
  *(u16x8*)&g.out[(size_t)wid * g.stride + g.ooff + sub * 8] = o;
}

// ---------------- MFMA GEMM (fused 3 dst-types per launch) ----------------

struct MJob { const unsigned short* A; const unsigned short* Wh; const unsigned short* Wl;
              const float* b0; const float* b1; float scale; int lrelu;
              float* H; int ldh; unsigned short* Hb; int M; int bstart; };
struct MArgs { MJob j[3]; };

template <int KCH, int NW>
__device__ __forceinline__ void mgemm_body(const MJob& p, int bxl) {
  constexpr int KP = KCH * 128;
  int t = threadIdx.x;
  int w = t >> 6, l = t & 63;
  int lo16 = l & 15, hi4 = l >> 4;
  int m0 = bxl * 64;
  int M = p.M;
  const unsigned short* A = p.A;
  f32x4 acc[4][NW] = {};
  for (int s = 0; s < KP / 32; ++s) {
    int kbase = s * 32 + hi4 * 8;
    bf16x8 af[4];
#pragma unroll
    for (int mf = 0; mf < 4; ++mf) {
      int row = m0 + mf * 16 + lo16;
      row = row < M ? row : M - 1;  // clamp; OOB rows never stored
      af[mf] = *(const bf16x8*)&A[(size_t)row * KP + kbase];
    }
#pragma unroll
    for (int nf = 0; nf < NW; ++nf) {
      int n = (w * NW + nf) * 16 + lo16;
      bf16x8 bh = *(const bf16x8*)&p.Wh[(size_t)n * KP + kbase];
      bf16x8 bl = *(const bf16x8*)&p.Wl[(size_t)n * KP + kbase];
#pragma unroll
      for (int mf = 0; mf < 4; ++mf) {
        acc[mf][nf] = __builtin_amdgcn_mfma_f32_16x16x32_bf16(af[mf], bh, acc[mf][nf], 0, 0, 0);
        acc[mf][nf] = __builtin_amdgcn_mfma_f32_16x16x32_bf16(af[mf], bl, acc[mf][nf], 0, 0, 0);
      }
    }
  }
#pragma unroll
  for (int nf = 0; nf < NW; ++nf) {
    int col = (w * NW + nf) * 16 + lo16;
    float bs = p.b0[col];
    if (p.b1) bs += p.b1[col];
#pragma unroll
    for (int mf = 0; mf < 4; ++mf) {
#pragma unroll
      for (int rr = 0; rr < 4; ++rr) {
        int row = m0 + mf * 16 + hi4 * 4 + rr;
        if (row < M) {
          float o = p.scale * (acc[mf][nf][rr] + bs);
          if (p.lrelu) o = o >= 0.f ? o : LRELU * o;
          if (p.H) p.H[(size_t)row * p.ldh + col] = o;
          if (p.Hb) p.Hb[(size_t)row * p.ldh + col] = f2bf(o);
        }
      }
    }
  }
}

__global__ __launch_bounds__(256) void k_mgemm3(MArgs a) {
  int bx = blockIdx.x;
  if (bx < a.j[1].bstart)      mgemm_body<2, 2>(a.j[0], bx);
  else if (bx < a.j[2].bstart) mgemm_body<2, 2>(a.j[1], bx - a.j[1].bstart);
  else                         mgemm_body<1, 2>(a.j[2], bx - a.j[2].bstart);
}

__global__ __launch_bounds__(256) void k_proj3(MArgs a) {
  int bx = blockIdx.x;
  if (bx < a.j[1].bstart)      mgemm_body<1, 1>(a.j[0], bx);
  else if (bx < a.j[2].bstart) mgemm_body<1, 1>(a.j[1], bx - a.j[1].bstart);
  else                         mgemm_body<1, 1>(a.j[2], bx - a.j[2].bstart);
}

// ---------------- host ----------------

extern "C" void kernel_launch(void* const* d_in, const int* in_sizes, int n_in,
                              void* d_out, int out_size, void* d_ws, size_t ws_size,
                              hipStream_t stream) {
  const float* xu = (const float*)d_in[0];
  const float* xn = (const float*)d_in[1];
  const float* xs = (const float*)d_in[2];
  const float* W1 = (const float*)d_in[3];
  const float* b1 = (const float*)d_in[4];
  const float* W2 = (const float*)d_in[5];
  const float* b2 = (const float*)d_in[6];
  const float* Wu = (const float*)d_in[7];
  const float* bu = (const float*)d_in[8];
  const float* Wn = (const float*)d_in[9];
  const float* bn = (const float*)d_in[10];
  const float* Wsrc = (const float*)d_in[11];
  const float* bsrc = (const float*)d_in[12];
  const int* SRC[5] = {(const int*)d_in[13], (const int*)d_in[15], (const int*)d_in[17],
                       (const int*)d_in[19], (const int*)d_in[21]};
  const int* DST[5] = {(const int*)d_in[14], (const int*)d_in[16], (const int*)d_in[18],
                       (const int*)d_in[20], (const int*)d_in[22]};

  // ---- workspace layout (~69.6 MB, matches proven R5 footprint) ----
  int* ws_i = (int*)d_ws;
  int* rp = ws_i;                           // 142008
  int* csr = ws_i + 142008;                 // 1400000
  int* pos = ws_i + 1542008;                // 1400000
  int* csums = ws_i + 2942008;              // 320
  int* cnt = ws_i + 2942328;                // 284000 (single copy)
  float* rs = (float*)(ws_i + 3226328);     // 284000
  unsigned short* wt = (unsigned short*)(rs + 284000);    // 376832
  unsigned short* aggU = wt + 376832;       // 50000*256
  unsigned short* aggN = aggU + 12800000;   // 20000*256
  unsigned short* aggS = aggN + 5120000;    // 2000*128
  unsigned short* xbU = aggS + 256000;      // 50000*128 (h1 then h2, bf16)
  unsigned short* xbN = xbU + 6400000;      // 20000*128
  unsigned short* xbS = xbN + 2560000;      // 2000*128

  // wt sub-offsets (hi, lo consecutive; L1 slots unused now)
  unsigned short* L2U_h = wt + 163840, * L2U_l = wt + 196608;
  unsigned short* L2N_h = wt + 229376, * L2N_l = wt + 262144;
  unsigned short* L2S_h = wt + 294912, * L2S_l = wt + 311296;
  unsigned short* PU_h = wt + 327680, * PU_l = wt + 335872;
  unsigned short* PN_h = wt + 344064, * PN_l = wt + 352256;
  unsigned short* PS_h = wt + 360448, * PS_l = wt + 368640;

  // ---- d_out layout ----
  float* outf = (float*)d_out;
  float* ou = outf;                 // 50000*64
  float* on = outf + 3200000;       // 20000*64
  float* osrc = outf + 4480000;     // 2000*64
  float* hu = outf + 4608000;       // 50000*128
  float* hn = outf + 11008000;      // 20000*128
  float* hs = outf + 13568000;      // 2000*128

  // layer-1 transform outputs Y_r (bf16) live in the hu/hn/hs region (36.4 MB
  // of 36.9 MB); consumed by k_gather1, dead before layer-2 mgemm3 overwrites.
  unsigned short* Yb = (unsigned short*)(outf + 4608000);
  unsigned short* Y0 = Yb;              // 50000*128 (follows, src U)
  unsigned short* Y1 = Y0 + 6400000;    // 50000*128 (posts, src U)
  unsigned short* Y2 = Y1 + 6400000;    // 20000*128 (posted_by, src N)
  unsigned short* Y3 = Y2 + 2560000;    // 2000*128  (publishes, src S)
  unsigned short* Y4 = Y3 + 256000;     // 20000*128 (published_by, src N)

  // ---- fused setup: graph count (atomic-bound) + transform GEMM + wprep ----
  hipMemsetAsync(cnt, 0, (size_t)284000 * 4, stream);
  SetupArgs su;
  for (int r = 0; r < 5; ++r)
    su.rel[r] = {SRC[r], DST[r], pos + CSR_OFF[r], DOUT_OFF[r], DIN_OFF[r], REL_E[r]};
  su.cnt = cnt;
  su.tj[0] = {xu, W1 + 0 * 16384, Y0, kNU};
  su.tj[1] = {xu, W1 + 1 * 16384, Y1, kNU};
  su.tj[2] = {xn, W1 + 2 * 16384, Y2, kNN};
  su.tj[3] = {xs, W1 + 3 * 16384, Y3, kNS};
  su.tj[4] = {xn, W1 + 4 * 16384, Y4, kNN};
  su.pj[0] = {W2, W2 + 2 * 16384, L2U_h, L2U_l, 128, 8, 0};
  su.pj[1] = {W2 + 16384, W2 + 3 * 16384, L2N_h, L2N_l, 128, 8, 128};
  su.pj[2] = {W2 + 4 * 16384, nullptr, L2S_h, L2S_l, 128, 7, 256};
  su.pj[3] = {Wu, nullptr, PU_h, PU_l, 64, 7, 320};
  su.pj[4] = {Wn, nullptr, PN_h, PN_l, 64, 7, 352};
  su.pj[5] = {Wsrc, nullptr, PS_h, PS_l, 64, 7, 384};
  k_setup<<<8108, 256, 0, stream>>>(su);

  // ---- rs + scan ----
  ScanArgs sa;
  for (int r = 0; r < 5; ++r) {
    sa.cnt[r] = cnt + DIN_OFF[r];
    sa.rp[r] = rp + RP_OFF[r];
    sa.n[r] = REL_ND[r];
  }
  sa.csums = csums;
  RsScanArgs rsa;
  rsa.cnt = cnt;
  rsa.rs = rs;
  rsa.sa = sa;
  k_rs_scan1<<<1250, 256, 0, stream>>>(rsa);
  k_scan3<<<140, 256, 0, stream>>>(sa);

  B2Args b2a;
  for (int r = 0; r < 5; ++r)
    b2a.rel[r] = {SRC[r], DST[r], rp + RP_OFF[r], pos + CSR_OFF[r],
                  csr + CSR_OFF[r], REL_E[r]};
  k_build2<<<5470, 256, 0, stream>>>(b2a);

  // ---- layer 1: gather Y -> h1 (bf16 into xb*, fused bias/mean/lrelu) ----
  G1Args g1;
  const unsigned short* YT[5] = {Y0, Y1, Y2, Y3, Y4};
  for (int r = 0; r < 5; ++r)
    g1.rel[r] = {rp + RP_OFF[r], csr + CSR_OFF[r], YT[r],
                 rs + DOUT_OFF[r], rs + DIN_OFF[r]};
  g1.b = b1;
  g1.hU = xbU; g1.hN = xbN; g1.hS = xbS;
  k_gather1<<<4500, 256, 0, stream>>>(g1);

  // ---- layer 2: gather h1 -> agg, then fused MFMA GEMM -> h2 ----
  {
    const unsigned short* XIN[5] = {xbU, xbU, xbN, xbS, xbN};
    unsigned short* OUT[5] = {aggU, aggN, aggU, aggN, aggS};
    const int OSTR[5] = {256, 256, 256, 256, 128};
    const int OOFF[5] = {0, 0, 128, 128, 0};
    GArgs ga;
    for (int r = 0; r < 5; ++r)
      ga.rel[r] = {rp + RP_OFF[r], csr + CSR_OFF[r], XIN[r], rs + DOUT_OFF[r],
                   rs + DIN_OFF[r], OUT[r], OSTR[r], OOFF[r], REL_ND[r]};
    k_gather<<<8875, 256, 0, stream>>>(ga);
    MArgs ma;
    ma.j[0] = {aggU, L2U_h, L2U_l, b2, b2 + 2 * 128, 0.5f, 1, hu, 128, xbU, kNU, 0};
    ma.j[1] = {aggN, L2N_h, L2N_l, b2 + 128, b2 + 3 * 128, 0.5f, 1, hn, 128, xbN, kNN, 782};
    ma.j[2] = {aggS, L2S_h, L2S_l, b2 + 4 * 128, nullptr, 1.0f, 1, hs, 128, xbS, kNS, 1095};
    k_mgemm3<<<1127, 256, 0, stream>>>(ma);
  }

  // ---- output projections (read bf16 h2 from xb*) ----
  MArgs pm;
  pm.j[0] = {xbU, PU_h, PU_l, bu, nullptr, 1.0f, 0, ou, 64, nullptr, kNU, 0};
  pm.j[1] = {xbN, PN_h, PN_l, bn, nullptr, 1.0f, 0, on, 64, nullptr, kNN, 782};
  pm.j[2] = {xbS, PS_h, PS_l, bsrc, nullptr, 1.0f, 0, osrc, 64, nullptr, kNS, 1095};
  k_proj3<<<1127, 256, 0, stream>>>(pm);
}

// Round 10
// 334.098 us; speedup vs baseline: 1.3774x; 1.1506x over previous
//
#include <hip/hip_runtime.h>

#define LRELU 0.01f

// ---------------- problem constants ----------------
// relations: 0 follows U->U, 1 posts U->N, 2 posted_by N->U, 3 publishes S->N, 4 published_by N->S
static const int kNU = 50000, kNN = 20000, kNS = 2000;
static const int REL_E[5]  = {500000, 300000, 300000, 150000, 150000};
static const int REL_ND[5] = {50000, 20000, 50000, 20000, 2000};
static const int DOUT_OFF[5] = {0, 100000, 170000, 240000, 262000};
static const int DIN_OFF[5]  = {50000, 150000, 190000, 242000, 282000};
static const int RP_OFF[5]   = {0, 50001, 70002, 120003, 140004};
static const int CSR_OFF[5]  = {0, 500000, 800000, 1100000, 1250000};
// dout-histogram geometry: per relation (src-space S, chunks C, ranges G, partial base PB)
static const int H_S[5]  = {50000, 50000, 20000, 2000, 20000};
static const int H_C[5]  = {31, 19, 19, 10, 10};
static const int H_PB[5] = {0, 1550000, 2500000, 2880000, 2900000};

using bf16x8 = __attribute__((ext_vector_type(8))) short;
using u16x8  = __attribute__((ext_vector_type(8))) unsigned short;
using f32x4  = __attribute__((ext_vector_type(4))) float;

__device__ __forceinline__ float bf2f(unsigned short u) {
  return __uint_as_float(((unsigned)u) << 16);
}
__device__ __forceinline__ unsigned short f2bf(float f) {  // RNE
  unsigned u = __float_as_uint(f);
  u += 0x7FFFu + ((u >> 16) & 1u);
  return (unsigned short)(u >> 16);
}

// ---------------- fused setup ----------------
// Roles striped 8 atomic : 5 other per 13 blocks. The din atomic (slot
// assignment, ~74us at the flat ~19G/s TCC atomic ceiling) shadows:
//   hist (805):      dout LDS-histograms -> non-atomic partial writes
//   transform (2222): layer-1 Y_r = bf16(x) @ (W1_r hi+lo) via MFMA
//   wprep (416):     layer-2/proj weight transpose + hi/lo split

struct RelB1 { const int* dst; int* pos; int dinoff; int E; };
struct HistRel { const int* src; int E; };
struct TJob  { const float* X; const float* W; unsigned short* Y; int M; };
struct PrepJob { const float* W0; const float* W128; unsigned short* hi;
                 unsigned short* lo; int NOUT; int lgK; int bstart; };
struct SetupArgs { RelB1 rel[5]; HistRel hr[5]; TJob tj[5]; PrepJob pj[6];
                   int* cnt; int* partial; };

__device__ __forceinline__ void transform_body(const TJob& p, int bxl, int t) {
  int w = t >> 6, l = t & 63;
  int lo16 = l & 15, hi4 = l >> 4;
  int m0 = bxl * 64;
  int M = p.M;
  f32x4 acc[4][2] = {};
  for (int s = 0; s < 4; ++s) {  // K = 128, 32 per step
    int kbase = s * 32 + hi4 * 8;
    bf16x8 af[4];
#pragma unroll
    for (int mf = 0; mf < 4; ++mf) {
      int row = m0 + mf * 16 + lo16;
      row = row < M ? row : M - 1;  // clamp; OOB rows never stored
      const float* xr = &p.X[(size_t)row * 128 + kbase];
      float4 xa = *(const float4*)xr;
      float4 xb = *(const float4*)(xr + 4);
      af[mf][0] = (short)f2bf(xa.x); af[mf][1] = (short)f2bf(xa.y);
      af[mf][2] = (short)f2bf(xa.z); af[mf][3] = (short)f2bf(xa.w);
      af[mf][4] = (short)f2bf(xb.x); af[mf][5] = (short)f2bf(xb.y);
      af[mf][6] = (short)f2bf(xb.z); af[mf][7] = (short)f2bf(xb.w);
    }
#pragma unroll
    for (int nf = 0; nf < 2; ++nf) {
      int n = (w * 2 + nf) * 16 + lo16;
      bf16x8 bh, bl;
#pragma unroll
      for (int j = 0; j < 8; ++j) {
        float wv = p.W[(size_t)(kbase + j) * 128 + n];
        unsigned short h = f2bf(wv);
        bh[j] = (short)h;
        bl[j] = (short)f2bf(wv - bf2f(h));
      }
#pragma unroll
      for (int mf = 0; mf < 4; ++mf) {
        acc[mf][nf] = __builtin_amdgcn_mfma_f32_16x16x32_bf16(af[mf], bh, acc[mf][nf], 0, 0, 0);
        acc[mf][nf] = __builtin_amdgcn_mfma_f32_16x16x32_bf16(af[mf], bl, acc[mf][nf], 0, 0, 0);
      }
    }
  }
#pragma unroll
  for (int nf = 0; nf < 2; ++nf) {
    int col = (w * 2 + nf) * 16 + lo16;
#pragma unroll
    for (int mf = 0; mf < 4; ++mf) {
#pragma unroll
      for (int rr = 0; rr < 4; ++rr) {
        int row = m0 + mf * 16 + hi4 * 4 + rr;
        if (row < M) p.Y[(size_t)row * 128 + col] = f2bf(acc[mf][nf][rr]);
      }
    }
  }
}

__global__ __launch_bounds__(256) void k_setup(SetupArgs a) {
  __shared__ int hbin[4096];
  int bx = blockIdx.x;
  int t = threadIdx.x;
  int role, idx;
  if (bx < 8892) {  // 684 groups of 13 = 8 atomic + 5 other
    int g = bx / 13, k = bx % 13;
    if (k < 8) { role = 0; idx = g * 8 + k; }
    else       { role = 1; idx = g * 5 + (k - 8); }
  } else {          // leftover others
    role = 1; idx = 3420 + (bx - 8892);
  }
  if (role == 0) {
    if (idx >= 5470) return;
    constexpr int ESTART[6] = {0, 1954, 3126, 4298, 4884, 5470};
    int r = 0;
    while (idx >= ESTART[r + 1]) ++r;
    RelB1 e = a.rel[r];
    int i = (idx - ESTART[r]) * 256 + t;
    if (i < e.E)
      e.pos[i] = atomicAdd(a.cnt + e.dinoff + e.dst[i], 1);
  } else if (idx < 805) {
    // dout histogram: block = (relation r, node-range g4k, edge-chunk c)
    constexpr int HSTART[6] = {0, 403, 650, 745, 755, 805};
    int r = 0;
    while (idx >= HSTART[r + 1]) ++r;
    int local = idx - HSTART[r];
    int C = H_C[r], S = H_S[r];
    int g4 = local / C, c = local % C;
    const int* src = a.hr[r].src;
    int E = a.hr[r].E;
    for (int j = t; j < 4096; j += 256) hbin[j] = 0;
    __syncthreads();
    int chunk = (E + C - 1) / C;
    int elo = c * chunk;
    int ehi = elo + chunk < E ? elo + chunk : E;
    int gbase = g4 * 4096;
    int gend = gbase + 4096 < S ? gbase + 4096 : S;
    for (int e = elo + t; e < ehi; e += 256) {
      int s = src[e];
      if (s >= gbase && s < gend) atomicAdd(&hbin[s - gbase], 1);
    }
    __syncthreads();
    int* dst = a.partial + (size_t)H_PB[r] + (size_t)c * S + gbase;
    for (int j = t; j < gend - gbase; j += 256) dst[j] = hbin[j];
  } else if (idx < 3027) {
    constexpr int TSTART[6] = {0, 782, 1564, 1877, 1909, 2222};
    int ti = idx - 805, r = 0;
    while (ti >= TSTART[r + 1]) ++r;
    transform_body(a.tj[r], ti - TSTART[r], t);
  } else {
    int b = idx - 3027, ji = 0;
    while (ji < 5 && b >= a.pj[ji + 1].bstart) ++ji;
    PrepJob p = a.pj[ji];
    int eidx = (b - p.bstart) * 256 + t;
    int K = 1 << p.lgK;
    int n = eidx >> p.lgK, k = eidx & (K - 1);
    if (n >= p.NOUT) return;
    float w = (k < 128) ? p.W0[k * p.NOUT + n] : p.W128[(k - 128) * p.NOUT + n];
    unsigned short h = f2bf(w);
    float res = w - bf2f(h);
    p.hi[n * K + k] = h;
    p.lo[n * K + k] = f2bf(res);
  }
}

// ---------------- fused rs (with dout partial-reduce) + scan1 ----------------

struct ScanArgs { const int* cnt[5]; int* rp[5]; int n[5]; int* csums; };
struct RsScanArgs { const int* cnt; const int* partial; float* rs; ScanArgs sa; };

__device__ __forceinline__ int dsum(const int* p, int PB, int C, int S, int node) {
  int s = 0;
  for (int c = 0; c < C; ++c) s += p[(size_t)PB + (size_t)c * S + node];
  return s;
}

__global__ __launch_bounds__(256) void k_rs_scan1(RsScanArgs a) {
  int bx = blockIdx.x;
  int t = threadIdx.x;
  if (bx < 1110) {
    int i = bx * 256 + t;
    if (i < 284000) {
      int cv;
      if      (i < 50000)  cv = dsum(a.partial, 0,       31, 50000, i);
      else if (i < 100000) cv = a.cnt[i];
      else if (i < 150000) cv = dsum(a.partial, 1550000, 19, 50000, i - 100000);
      else if (i < 170000) cv = a.cnt[i];
      else if (i < 190000) cv = dsum(a.partial, 2500000, 19, 20000, i - 170000);
      else if (i < 240000) cv = a.cnt[i];
      else if (i < 242000) cv = dsum(a.partial, 2880000, 10, 2000,  i - 240000);
      else if (i < 262000) cv = a.cnt[i];
      else if (i < 282000) cv = dsum(a.partial, 2900000, 10, 20000, i - 262000);
      else                 cv = a.cnt[i];
      a.rs[i] = rsqrtf((float)(cv > 1 ? cv : 1));
    }
    return;
  }
  bx -= 1110;
  constexpr int CSTART[6] = {0, 49, 69, 118, 138, 140};
  int r = 0;
  while (bx >= CSTART[r + 1]) ++r;
  int chunk = bx - CSTART[r];
  int n = a.sa.n[r];
  int base = chunk * 1024;
  const int* cnt = a.sa.cnt[r];
  int s = 0;
#pragma unroll
  for (int j = 0; j < 4; ++j) {
    int idx = base + j * 256 + t;
    if (idx < n) s += cnt[idx];
  }
  __shared__ int sd[256];
  sd[t] = s;
  __syncthreads();
  for (int off = 128; off > 0; off >>= 1) {
    if (t < off) sd[t] += sd[t + off];
    __syncthreads();
  }
  if (t == 0) a.sa.csums[r * 64 + chunk] = sd[0];
}

// ---------------- scan3: local scan + in-block chunk-prefix ----------------

__global__ __launch_bounds__(256) void k_scan3(ScanArgs a) {
  constexpr int CSTART[6] = {0, 49, 69, 118, 138, 140};
  int bx = blockIdx.x, r = 0;
  while (bx >= CSTART[r + 1]) ++r;
  int chunk = bx - CSTART[r];
  int nch = CSTART[r + 1] - CSTART[r];
  int n = a.n[r];
  int base = chunk * 1024;
  const int* cnt = a.cnt[r];
  int* rp = a.rp[r];
  int t = threadIdx.x;
  int idx0 = base + t * 4;
  int v[4];
#pragma unroll
  for (int j = 0; j < 4; ++j) v[j] = (idx0 + j < n) ? cnt[idx0 + j] : 0;
  int tsum = v[0] + v[1] + v[2] + v[3];
  __shared__ int sd[256];
  __shared__ int choff_sh;
  sd[t] = tsum;
  if (t < 64) {  // prefix of earlier chunk sums, wave reduce
    int cv = (t < chunk) ? a.csums[r * 64 + t] : 0;
    for (int o = 32; o > 0; o >>= 1) cv += __shfl_down(cv, o);
    if (t == 0) choff_sh = cv;
  }
  __syncthreads();
  for (int s = 1; s < 256; s <<= 1) {
    int add = (t >= s) ? sd[t - s] : 0;
    __syncthreads();
    sd[t] += add;
    __syncthreads();
  }
  int off = choff_sh + sd[t] - tsum;
#pragma unroll
  for (int j = 0; j < 4; ++j) {
    if (idx0 + j < n) rp[idx0 + j] = off;
    off += v[j];
  }
  if (chunk == nch - 1 && t == 255) rp[n] = choff_sh + sd[255];
}

// ---------------- build2: atomic-free CSR scatter ----------------

struct RelB2 { const int* src; const int* dst; const int* rp; const int* pos; int* csr; int E; };
struct B2Args { RelB2 rel[5]; };

__global__ __launch_bounds__(256) void k_build2(B2Args a) {
  constexpr int ESTART[6] = {0, 1954, 3126, 4298, 4884, 5470};
  int bx = blockIdx.x, r = 0;
  while (bx >= ESTART[r + 1]) ++r;
  RelB2 f = a.rel[r];
  int i = (bx - ESTART[r]) * 256 + threadIdx.x;
  if (i < f.E) {
    int d = f.dst[i];
    f.csr[f.rp[d] + f.pos[i]] = f.src[i];
  }
}

// ---------------- shared gather inner loop ----------------
// 16 lanes per dst row; 16-edge batches: coalesced csr read + parallel rso
// gathers, width-16 shfl broadcast. Full batches keep 16 row-loads in flight.

#define GROW(vv, cc)                                                              \
  _Pragma("unroll") for (int q = 0; q < 8; ++q)                                   \
      acc[q] = fmaf(__uint_as_float(((unsigned)(unsigned short)vv[q]) << 16), cc, acc[q]);

__device__ __forceinline__ void gat_accum(const int* __restrict__ rp,
    const int* __restrict__ csr, const unsigned short* __restrict__ Y,
    const float* __restrict__ rso, int wid, int sub, float* acc) {
  int e0 = rp[wid], e1 = rp[wid + 1];
  for (int base = e0; base < e1; base += 16) {
    int m = e1 - base;
    if (m > 16) m = 16;
    int ei = base + (sub < m ? sub : 0);
    int se = csr[ei];
    float sc = rso[se];
    if (m == 16) {
      bf16x8 v[16];
#pragma unroll
      for (int j = 0; j < 16; ++j) {
        int sj = __shfl(se, j, 16);
        v[j] = *(const bf16x8*)&Y[(size_t)sj * 128 + sub * 8];
      }
#pragma unroll
      for (int j = 0; j < 16; ++j) {
        float cj = __shfl(sc, j, 16);
        GROW(v[j], cj)
      }
    } else {
      int j = 0;
      for (; j + 8 <= m; j += 8) {
        int s0 = __shfl(se, j, 16), s1 = __shfl(se, j + 1, 16);
        int s2 = __shfl(se, j + 2, 16), s3 = __shfl(se, j + 3, 16);
        int s4 = __shfl(se, j + 4, 16), s5 = __shfl(se, j + 5, 16);
        int s6 = __shfl(se, j + 6, 16), s7 = __shfl(se, j + 7, 16);
        float c0 = __shfl(sc, j, 16), c1 = __shfl(sc, j + 1, 16);
        float c2 = __shfl(sc, j + 2, 16), c3 = __shfl(sc, j + 3, 16);
        float c4 = __shfl(sc, j + 4, 16), c5 = __shfl(sc, j + 5, 16);
        float c6 = __shfl(sc, j + 6, 16), c7 = __shfl(sc, j + 7, 16);
        bf16x8 v0 = *(const bf16x8*)&Y[(size_t)s0 * 128 + sub * 8];
        bf16x8 v1 = *(const bf16x8*)&Y[(size_t)s1 * 128 + sub * 8];
        bf16x8 v2 = *(const bf16x8*)&Y[(size_t)s2 * 128 + sub * 8];
        bf16x8 v3 = *(const bf16x8*)&Y[(size_t)s3 * 128 + sub * 8];
        bf16x8 v4 = *(const bf16x8*)&Y[(size_t)s4 * 128 + sub * 8];
        bf16x8 v5 = *(const bf16x8*)&Y[(size_t)s5 * 128 + sub * 8];
        bf16x8 v6 = *(const bf16x8*)&Y[(size_t)s6 * 128 + sub * 8];
        bf16x8 v7 = *(const bf16x8*)&Y[(size_t)s7 * 128 + sub * 8];
        GROW(v0, c0) GROW(v1, c1) GROW(v2, c2) GROW(v3, c3)
        GROW(v4, c4) GROW(v5, c5) GROW(v6, c6) GROW(v7, c7)
      }
      for (; j < m; ++j) {
        int s0 = __shfl(se, j, 16);
        float c0 = __shfl(sc, j, 16);
        bf16x8 v0 = *(const bf16x8*)&Y[(size_t)s0 * 128 + sub * 8];
        GROW(v0, c0)
      }
    }
  }
}

// ---------------- layer-1 gather: Y -> h1 (bias + mean + lrelu fused) ----------------

struct G1Rel { const int* rp; const int* csr; const unsigned short* Y;
               const float* rso; const float* rsi; };
struct G1Args { G1Rel rel[5]; const float* b;
                unsigned short* hU; unsigned short* hN; unsigned short* hS; };

__global__ __launch_bounds__(256) void k_gather1(G1Args a) {
  int bx = blockIdx.x;
  int t = threadIdx.x;
  int sub = t & 15;
  float acc[8], tot[8];
#pragma unroll
  for (int q = 0; q < 8; ++q) acc[q] = 0.f;
  if (bx < 3125) {  // users: rel 0 + rel 2
    int wid = bx * 16 + (t >> 4);
    gat_accum(a.rel[0].rp, a.rel[0].csr, a.rel[0].Y, a.rel[0].rso, wid, sub, acc);
    float s0 = a.rel[0].rsi[wid];
#pragma unroll
    for (int q = 0; q < 8; ++q) { tot[q] = s0 * acc[q]; acc[q] = 0.f; }
    gat_accum(a.rel[2].rp, a.rel[2].csr, a.rel[2].Y, a.rel[2].rso, wid, sub, acc);
    float s2 = a.rel[2].rsi[wid];
    const float* b0 = a.b;
    const float* b2 = a.b + 2 * 128;
    u16x8 o;
#pragma unroll
    for (int q = 0; q < 8; ++q) {
      float v = 0.5f * (tot[q] + s2 * acc[q] + b0[sub * 8 + q] + b2[sub * 8 + q]);
      v = v >= 0.f ? v : LRELU * v;
      o[q] = f2bf(v);
    }
    *(u16x8*)&a.hU[(size_t)wid * 128 + sub * 8] = o;
  } else if (bx < 4375) {  // news: rel 1 + rel 3
    int wid = (bx - 3125) * 16 + (t >> 4);
    gat_accum(a.rel[1].rp, a.rel[1].csr, a.rel[1].Y, a.rel[1].rso, wid, sub, acc);
    float s1 = a.rel[1].rsi[wid];
#pragma unroll
    for (int q = 0; q < 8; ++q) { tot[q] = s1 * acc[q]; acc[q] = 0.f; }
    gat_accum(a.rel[3].rp, a.rel[3].csr, a.rel[3].Y, a.rel[3].rso, wid, sub, acc);
    float s3 = a.rel[3].rsi[wid];
    const float* b1v = a.b + 128;
    const float* b3 = a.b + 3 * 128;
    u16x8 o;
#pragma unroll
    for (int q = 0; q < 8; ++q) {
      float v = 0.5f * (tot[q] + s3 * acc[q] + b1v[sub * 8 + q] + b3[sub * 8 + q]);
      v = v >= 0.f ? v : LRELU * v;
      o[q] = f2bf(v);
    }
    *(u16x8*)&a.hN[(size_t)wid * 128 + sub * 8] = o;
  } else {  // sources: rel 4
    int wid = (bx - 4375) * 16 + (t >> 4);
    gat_accum(a.rel[4].rp, a.rel[4].csr, a.rel[4].Y, a.rel[4].rso, wid, sub, acc);
    float s4 = a.rel[4].rsi[wid];
    const float* b4 = a.b + 4 * 128;
    u16x8 o;
#pragma unroll
    for (int q = 0; q < 8; ++q) {
      float v = s4 * acc[q] + b4[sub * 8 + q];
      v = v >= 0.f ? v : LRELU * v;
      o[q] = f2bf(v);
    }
    *(u16x8*)&a.hS[(size_t)wid * 128 + sub * 8] = o;
  }
}

// ---------------- layer-2 gather (h1 -> agg, bf16) ----------------

struct RelG {
  const int* rp; const int* csr; const unsigned short* xb;
  const float* rso; const float* rsi;
  unsigned short* out; int stride; int ooff; int nd;
};
struct GArgs { RelG rel[5]; };

__global__ __launch_bounds__(256) void k_gather(GArgs a) {
  constexpr int GSTART[6] = {0, 3125, 4375, 7500, 8750, 8875};
  int bx = blockIdx.x, r = 0;
  while (bx >= GSTART[r + 1]) ++r;
  RelG g = a.rel[r];
  int t = threadIdx.x;
  int sub = t & 15;
  int wid = (bx - GSTART[r]) * 16 + (t >> 4);
  if (wid >= g.nd) return;
  float acc[8];
#pragma unroll
  for (int q = 0; q < 8; ++q) acc[q] = 0.f;
  gat_accum(g.rp, g.csr, g.xb, g.rso, wid, sub, acc);
  float si = g.rsi[wid];
  u16x8 o;
#pragma unroll
  for (int q = 0; q < 8; ++q) o[q] = f2bf(acc[q] * si);
  *(u16x8*)&g.out[(size_t)wid * g.stride + g.ooff + sub * 8] = o;
}

// ---------------- MFMA GEMM (fused 3 dst-types per launch) ----------------

struct MJob { const unsigned short* A; const unsigned short* Wh; const unsigned short* Wl;
              const float* b0; const float* b1; float scale; int lrelu;
              float* H; int ldh; unsigned short* Hb; int M; int bstart; };
struct MArgs { MJob j[3]; };

template <int KCH, int NW>
__device__ __forceinline__ void mgemm_body(const MJob& p, int bxl) {
  constexpr int KP = KCH * 128;
  int t = threadIdx.x;
  int w = t >> 6, l = t & 63;
  int lo16 = l & 15, hi4 = l >> 4;
  int m0 = bxl * 64;
  int M = p.M;
  const unsigned short* A = p.A;
  f32x4 acc[4][NW] = {};
  for (int s = 0; s < KP / 32; ++s) {
    int kbase = s * 32 + hi4 * 8;
    bf16x8 af[4];
#pragma unroll
    for (int mf = 0; mf < 4; ++mf) {
      int row = m0 + mf * 16 + lo16;
      row = row < M ? row : M - 1;  // clamp; OOB rows never stored
      af[mf] = *(const bf16x8*)&A[(size_t)row * KP + kbase];
    }
#pragma unroll
    for (int nf = 0; nf < NW; ++nf) {
      int n = (w * NW + nf) * 16 + lo16;
      bf16x8 bh = *(const bf16x8*)&p.Wh[(size_t)n * KP + kbase];
      bf16x8 bl = *(const bf16x8*)&p.Wl[(size_t)n * KP + kbase];
#pragma unroll
      for (int mf = 0; mf < 4; ++mf) {
        acc[mf][nf] = __builtin_amdgcn_mfma_f32_16x16x32_bf16(af[mf], bh, acc[mf][nf], 0, 0, 0);
        acc[mf][nf] = __builtin_amdgcn_mfma_f32_16x16x32_bf16(af[mf], bl, acc[mf][nf], 0, 0, 0);
      }
    }
  }
#pragma unroll
  for (int nf = 0; nf < NW; ++nf) {
    int col = (w * NW + nf) * 16 + lo16;
    float bs = p.b0[col];
    if (p.b1) bs += p.b1[col];
#pragma unroll
    for (int mf = 0; mf < 4; ++mf) {
#pragma unroll
      for (int rr = 0; rr < 4; ++rr) {
        int row = m0 + mf * 16 + hi4 * 4 + rr;
        if (row < M) {
          float o = p.scale * (acc[mf][nf][rr] + bs);
          if (p.lrelu) o = o >= 0.f ? o : LRELU * o;
          if (p.H) p.H[(size_t)row * p.ldh + col] = o;
          if (p.Hb) p.Hb[(size_t)row * p.ldh + col] = f2bf(o);
        }
      }
    }
  }
}

__global__ __launch_bounds__(256) void k_mgemm3(MArgs a) {
  int bx = blockIdx.x;
  if (bx < a.j[1].bstart)      mgemm_body<2, 2>(a.j[0], bx);
  else if (bx < a.j[2].bstart) mgemm_body<2, 2>(a.j[1], bx - a.j[1].bstart);
  else                         mgemm_body<1, 2>(a.j[2], bx - a.j[2].bstart);
}

__global__ __launch_bounds__(256) void k_proj3(MArgs a) {
  int bx = blockIdx.x;
  if (bx < a.j[1].bstart)      mgemm_body<1, 1>(a.j[0], bx);
  else if (bx < a.j[2].bstart) mgemm_body<1, 1>(a.j[1], bx - a.j[1].bstart);
  else                         mgemm_body<1, 1>(a.j[2], bx - a.j[2].bstart);
}

// ---------------- host ----------------

extern "C" void kernel_launch(void* const* d_in, const int* in_sizes, int n_in,
                              void* d_out, int out_size, void* d_ws, size_t ws_size,
                              hipStream_t stream) {
  const float* xu = (const float*)d_in[0];
  const float* xn = (const float*)d_in[1];
  const float* xs = (const float*)d_in[2];
  const float* W1 = (const float*)d_in[3];
  const float* b1 = (const float*)d_in[4];
  const float* W2 = (const float*)d_in[5];
  const float* b2 = (const float*)d_in[6];
  const float* Wu = (const float*)d_in[7];
  const float* bu = (const float*)d_in[8];
  const float* Wn = (const float*)d_in[9];
  const float* bn = (const float*)d_in[10];
  const float* Wsrc = (const float*)d_in[11];
  const float* bsrc = (const float*)d_in[12];
  const int* SRC[5] = {(const int*)d_in[13], (const int*)d_in[15], (const int*)d_in[17],
                       (const int*)d_in[19], (const int*)d_in[21]};
  const int* DST[5] = {(const int*)d_in[14], (const int*)d_in[16], (const int*)d_in[18],
                       (const int*)d_in[20], (const int*)d_in[22]};

  // ---- workspace layout (~69.6 MB) ----
  int* ws_i = (int*)d_ws;
  int* rp = ws_i;                           // 142008
  int* csr = ws_i + 142008;                 // 1400000
  int* pos = ws_i + 1542008;                // 1400000
  int* csums = ws_i + 2942008;              // 320
  int* cnt = ws_i + 2942328;                // 284000 (din halves used)
  float* rs = (float*)(ws_i + 3226328);     // 284000
  unsigned short* wt = (unsigned short*)(rs + 284000);    // 376832
  unsigned short* aggU = wt + 376832;       // 50000*256
  unsigned short* aggN = aggU + 12800000;   // 20000*256
  unsigned short* aggS = aggN + 5120000;    // 2000*128
  unsigned short* xbU = aggS + 256000;      // 50000*128 (h1 then h2, bf16)
  unsigned short* xbN = xbU + 6400000;      // 20000*128
  unsigned short* xbS = xbN + 2560000;      // 2000*128

  // wt sub-offsets (hi, lo consecutive)
  unsigned short* L2U_h = wt + 163840, * L2U_l = wt + 196608;
  unsigned short* L2N_h = wt + 229376, * L2N_l = wt + 262144;
  unsigned short* L2S_h = wt + 294912, * L2S_l = wt + 311296;
  unsigned short* PU_h = wt + 327680, * PU_l = wt + 335872;
  unsigned short* PN_h = wt + 344064, * PN_l = wt + 352256;
  unsigned short* PS_h = wt + 360448, * PS_l = wt + 368640;

  // ---- d_out layout ----
  float* outf = (float*)d_out;
  float* ou = outf;                 // 50000*64
  float* on = outf + 3200000;       // 20000*64
  float* osrc = outf + 4480000;     // 2000*64
  float* hu = outf + 4608000;       // 50000*128
  float* hn = outf + 11008000;      // 20000*128
  float* hs = outf + 13568000;      // 2000*128

  // dout histogram partials (3.1M ints = 12.4 MB) live in ou's slot (12.8 MB)
  // -- dead until k_proj3; consumed by k_rs_scan1.
  int* partial = (int*)ou;

  // layer-1 transform outputs Y_r (bf16) live in the hu/hn/hs region;
  // consumed by k_gather1, dead before layer-2 mgemm3 overwrites.
  unsigned short* Yb = (unsigned short*)(outf + 4608000);
  unsigned short* Y0 = Yb;              // 50000*128 (follows, src U)
  unsigned short* Y1 = Y0 + 6400000;    // 50000*128 (posts, src U)
  unsigned short* Y2 = Y1 + 6400000;    // 20000*128 (posted_by, src N)
  unsigned short* Y3 = Y2 + 2560000;    // 2000*128  (publishes, src S)
  unsigned short* Y4 = Y3 + 256000;     // 20000*128 (published_by, src N)

  // ---- fused setup: din atomics + dout hist + transform GEMM + wprep ----
  hipMemsetAsync(cnt, 0, (size_t)284000 * 4, stream);
  SetupArgs su;
  for (int r = 0; r < 5; ++r) {
    su.rel[r] = {DST[r], pos + CSR_OFF[r], DIN_OFF[r], REL_E[r]};
    su.hr[r] = {SRC[r], REL_E[r]};
  }
  su.cnt = cnt;
  su.partial = partial;
  su.tj[0] = {xu, W1 + 0 * 16384, Y0, kNU};
  su.tj[1] = {xu, W1 + 1 * 16384, Y1, kNU};
  su.tj[2] = {xn, W1 + 2 * 16384, Y2, kNN};
  su.tj[3] = {xs, W1 + 3 * 16384, Y3, kNS};
  su.tj[4] = {xn, W1 + 4 * 16384, Y4, kNN};
  su.pj[0] = {W2, W2 + 2 * 16384, L2U_h, L2U_l, 128, 8, 0};
  su.pj[1] = {W2 + 16384, W2 + 3 * 16384, L2N_h, L2N_l, 128, 8, 128};
  su.pj[2] = {W2 + 4 * 16384, nullptr, L2S_h, L2S_l, 128, 7, 256};
  su.pj[3] = {Wu, nullptr, PU_h, PU_l, 64, 7, 320};
  su.pj[4] = {Wn, nullptr, PN_h, PN_l, 64, 7, 352};
  su.pj[5] = {Wsrc, nullptr, PS_h, PS_l, 64, 7, 384};
  k_setup<<<8915, 256, 0, stream>>>(su);

  // ---- rs (+dout reduce) + scan ----
  ScanArgs sa;
  for (int r = 0; r < 5; ++r) {
    sa.cnt[r] = cnt + DIN_OFF[r];
    sa.rp[r] = rp + RP_OFF[r];
    sa.n[r] = REL_ND[r];
  }
  sa.csums = csums;
  RsScanArgs rsa;
  rsa.cnt = cnt;
  rsa.partial = partial;
  rsa.rs = rs;
  rsa.sa = sa;
  k_rs_scan1<<<1250, 256, 0, stream>>>(rsa);
  k_scan3<<<140, 256, 0, stream>>>(sa);

  B2Args b2a;
  for (int r = 0; r < 5; ++r)
    b2a.rel[r] = {SRC[r], DST[r], rp + RP_OFF[r], pos + CSR_OFF[r],
                  csr + CSR_OFF[r], REL_E[r]};
  k_build2<<<5470, 256, 0, stream>>>(b2a);

  // ---- layer 1: gather Y -> h1 (bf16 into xb*, fused bias/mean/lrelu) ----
  G1Args g1;
  const unsigned short* YT[5] = {Y0, Y1, Y2, Y3, Y4};
  for (int r = 0; r < 5; ++r)
    g1.rel[r] = {rp + RP_OFF[r], csr + CSR_OFF[r], YT[r],
                 rs + DOUT_OFF[r], rs + DIN_OFF[r]};
  g1.b = b1;
  g1.hU = xbU; g1.hN = xbN; g1.hS = xbS;
  k_gather1<<<4500, 256, 0, stream>>>(g1);

  // ---- layer 2: gather h1 -> agg, then fused MFMA GEMM -> h2 ----
  {
    const unsigned short* XIN[5] = {xbU, xbU, xbN, xbS, xbN};
    unsigned short* OUT[5] = {aggU, aggN, aggU, aggN, aggS};
    const int OSTR[5] = {256, 256, 256, 256, 128};
    const int OOFF[5] = {0, 0, 128, 128, 0};
    GArgs ga;
    for (int r = 0; r < 5; ++r)
      ga.rel[r] = {rp + RP_OFF[r], csr + CSR_OFF[r], XIN[r], rs + DOUT_OFF[r],
                   rs + DIN_OFF[r], OUT[r], OSTR[r], OOFF[r], REL_ND[r]};
    k_gather<<<8875, 256, 0, stream>>>(ga);
    MArgs ma;
    ma.j[0] = {aggU, L2U_h, L2U_l, b2, b2 + 2 * 128, 0.5f, 1, hu, 128, xbU, kNU, 0};
    ma.j[1] = {aggN, L2N_h, L2N_l, b2 + 128, b2 + 3 * 128, 0.5f, 1, hn, 128, xbN, kNN, 782};
    ma.j[2] = {aggS, L2S_h, L2S_l, b2 + 4 * 128, nullptr, 1.0f, 1, hs, 128, xbS, kNS, 1095};
    k_mgemm3<<<1127, 256, 0, stream>>>(ma);
  }

  // ---- output projections (read bf16 h2 from xb*) ----
  MArgs pm;
  pm.j[0] = {xbU, PU_h, PU_l, bu, nullptr, 1.0f, 0, ou, 64, nullptr, kNU, 0};
  pm.j[1] = {xbN, PN_h, PN_l, bn, nullptr, 1.0f, 0, on, 64, nullptr, kNN, 782};
  pm.j[2] = {xbS, PS_h, PS_l, bsrc, nullptr, 1.0f, 0, osrc, 64, nullptr, kNS, 1095};
  k_proj3<<<1127, 256, 0, stream>>>(pm);
}

// Round 11
// 330.488 us; speedup vs baseline: 1.3925x; 1.0109x over previous
//
#include <hip/hip_runtime.h>

#define LRELU 0.01f

// ---------------- problem constants ----------------
// relations: 0 follows U->U, 1 posts U->N, 2 posted_by N->U, 3 publishes S->N, 4 published_by N->S
static const int kNU = 50000, kNN = 20000, kNS = 2000;
static const int DOUT_OFF[5] = {0, 100000, 170000, 240000, 262000};
static const int DIN_OFF[5]  = {50000, 150000, 190000, 242000, 282000};
static const int RP_OFF[5]   = {0, 50001, 70002, 120003, 140004};
static const int CSR_OFF[5]  = {0, 500000, 800000, 1100000, 1250000};

using bf16x8 = __attribute__((ext_vector_type(8))) short;
using u16x8  = __attribute__((ext_vector_type(8))) unsigned short;
using f32x4  = __attribute__((ext_vector_type(4))) float;

__device__ __forceinline__ float bf2f(unsigned short u) {
  return __uint_as_float(((unsigned)u) << 16);
}
__device__ __forceinline__ unsigned short f2bf(float f) {  // RNE
  unsigned u = __float_as_uint(f);
  u += 0x7FFFu + ((u >> 16) & 1u);
  return (unsigned short)(u >> 16);
}

// ---------------- phase A: LDS histograms (din rank + dout) + transform + wprep ----------------
// NO fabric atomics. din blocks also record each edge's within-(dst,chunk)
// rank from the LDS atomicAdd return -> pos[e]. 16 chunks per relation,
// 8192-node ranges (32KB LDS).

struct TJob { const float* X; const float* W; unsigned short* Y; int M; };
struct PrepJob { const float* W0; const float* W128; unsigned short* hi;
                 unsigned short* lo; int NOUT; int lgK; int bstart; };
struct AArgs { const int* esrc[5]; const int* edst[5]; int* pos; int* partial;
               TJob tj[5]; PrepJob pj[6]; };

__device__ __forceinline__ void transform_body(const TJob& p, int bxl, int t) {
  int w = t >> 6, l = t & 63;
  int lo16 = l & 15, hi4 = l >> 4;
  int m0 = bxl * 64;
  int M = p.M;
  f32x4 acc[4][2] = {};
  for (int s = 0; s < 4; ++s) {  // K = 128, 32 per step
    int kbase = s * 32 + hi4 * 8;
    bf16x8 af[4];
#pragma unroll
    for (int mf = 0; mf < 4; ++mf) {
      int row = m0 + mf * 16 + lo16;
      row = row < M ? row : M - 1;  // clamp; OOB rows never stored
      const float* xr = &p.X[(size_t)row * 128 + kbase];
      float4 xa = *(const float4*)xr;
      float4 xb = *(const float4*)(xr + 4);
      af[mf][0] = (short)f2bf(xa.x); af[mf][1] = (short)f2bf(xa.y);
      af[mf][2] = (short)f2bf(xa.z); af[mf][3] = (short)f2bf(xa.w);
      af[mf][4] = (short)f2bf(xb.x); af[mf][5] = (short)f2bf(xb.y);
      af[mf][6] = (short)f2bf(xb.z); af[mf][7] = (short)f2bf(xb.w);
    }
#pragma unroll
    for (int nf = 0; nf < 2; ++nf) {
      int n = (w * 2 + nf) * 16 + lo16;
      bf16x8 bh, bl;
#pragma unroll
      for (int j = 0; j < 8; ++j) {
        float wv = p.W[(size_t)(kbase + j) * 128 + n];
        unsigned short h = f2bf(wv);
        bh[j] = (short)h;
        bl[j] = (short)f2bf(wv - bf2f(h));
      }
#pragma unroll
      for (int mf = 0; mf < 4; ++mf) {
        acc[mf][nf] = __builtin_amdgcn_mfma_f32_16x16x32_bf16(af[mf], bh, acc[mf][nf], 0, 0, 0);
        acc[mf][nf] = __builtin_amdgcn_mfma_f32_16x16x32_bf16(af[mf], bl, acc[mf][nf], 0, 0, 0);
      }
    }
  }
#pragma unroll
  for (int nf = 0; nf < 2; ++nf) {
    int col = (w * 2 + nf) * 16 + lo16;
#pragma unroll
    for (int mf = 0; mf < 4; ++mf) {
#pragma unroll
      for (int rr = 0; rr < 4; ++rr) {
        int row = m0 + mf * 16 + hi4 * 4 + rr;
        if (row < M) p.Y[(size_t)row * 128 + col] = f2bf(acc[mf][nf][rr]);
      }
    }
  }
}

__global__ __launch_bounds__(256) void k_histA(AArgs a) {
  __shared__ int hbin[8192];
  int bx = blockIdx.x;
  int t = threadIdx.x;
  if (bx < 336) {
    // din rank-histogram: block = (rel r, dst-range g, edge-chunk c)
    constexpr int DSTART[6] = {0, 112, 160, 272, 320, 336};
    constexpr int NDT[5] = {50000, 20000, 50000, 20000, 2000};
    constexpr int CS[5]  = {31250, 18750, 18750, 9375, 9375};
    constexpr int EE[5]  = {500000, 300000, 300000, 150000, 150000};
    constexpr int PB[5]  = {0, 800000, 1120000, 1920000, 2240000};
    constexpr int COFF[5] = {0, 500000, 800000, 1100000, 1250000};
    int r = 0;
    while (bx >= DSTART[r + 1]) ++r;
    int local = bx - DSTART[r];
    int g = local >> 4, c = local & 15;
    int nd = NDT[r];
    int gbase = g * 8192;
    int gend = gbase + 8192 < nd ? gbase + 8192 : nd;
    const int* dst = a.edst[r];
    int* pos = a.pos + COFF[r];
    int elo = c * CS[r];
    int ehi = elo + CS[r] < EE[r] ? elo + CS[r] : EE[r];
    for (int j = t; j < 8192; j += 256) hbin[j] = 0;
    __syncthreads();
    for (int e = elo + t; e < ehi; e += 256) {
      int d = dst[e];
      if (d >= gbase && d < gend) pos[e] = atomicAdd(&hbin[d - gbase], 1);
    }
    __syncthreads();
    int* out = a.partial + PB[r] + (size_t)c * nd + gbase;
    int nn = gend - gbase;
    for (int j = t; j < nn; j += 256) out[j] = hbin[j];
  } else if (bx < 672) {
    // dout histogram (counts only)
    constexpr int OSTART[6] = {0, 112, 224, 272, 288, 336};
    constexpr int NST[5] = {50000, 50000, 20000, 2000, 20000};
    constexpr int CS[5]  = {31250, 18750, 18750, 9375, 9375};
    constexpr int EE[5]  = {500000, 300000, 300000, 150000, 150000};
    constexpr int PB[5]  = {2272000, 3072000, 3872000, 4192000, 4224000};
    int idx = bx - 336;
    int r = 0;
    while (idx >= OSTART[r + 1]) ++r;
    int local = idx - OSTART[r];
    int g = local >> 4, c = local & 15;
    int ns = NST[r];
    int gbase = g * 8192;
    int gend = gbase + 8192 < ns ? gbase + 8192 : ns;
    const int* src = a.esrc[r];
    int elo = c * CS[r];
    int ehi = elo + CS[r] < EE[r] ? elo + CS[r] : EE[r];
    for (int j = t; j < 8192; j += 256) hbin[j] = 0;
    __syncthreads();
    for (int e = elo + t; e < ehi; e += 256) {
      int s = src[e];
      if (s >= gbase && s < gend) atomicAdd(&hbin[s - gbase], 1);
    }
    __syncthreads();
    int* out = a.partial + PB[r] + (size_t)c * ns + gbase;
    int nn = gend - gbase;
    for (int j = t; j < nn; j += 256) out[j] = hbin[j];
  } else if (bx < 2894) {
    constexpr int TSTART[6] = {0, 782, 1564, 1877, 1909, 2222};
    int ti = bx - 672, r = 0;
    while (ti >= TSTART[r + 1]) ++r;
    transform_body(a.tj[r], ti - TSTART[r], t);
  } else {
    int b = bx - 2894, ji = 0;
    while (ji < 5 && b >= a.pj[ji + 1].bstart) ++ji;
    PrepJob p = a.pj[ji];
    int eidx = (b - p.bstart) * 256 + t;
    int K = 1 << p.lgK;
    int n = eidx >> p.lgK, k = eidx & (K - 1);
    if (n >= p.NOUT) return;
    float w = (k < 128) ? p.W0[k * p.NOUT + n] : p.W128[(k - 128) * p.NOUT + n];
    unsigned short h = f2bf(w);
    float res = w - bf2f(h);
    p.hi[n * K + k] = h;
    p.lo[n * K + k] = f2bf(res);
  }
}

// ---------------- phase B: chunk-prefix (din, in-place) + rs + cnt ----------------

struct BArgs { int* partial; int* cnt; float* rs; };

__global__ __launch_bounds__(256) void k_scanB(BArgs a) {
  int bx = blockIdx.x;
  int t = threadIdx.x;
  if (bx < 555) {
    int i = bx * 256 + t;
    if (i >= 142000) return;
    constexpr int NDT[5] = {50000, 20000, 50000, 20000, 2000};
    constexpr int PB[5]  = {0, 800000, 1120000, 1920000, 2240000};
    constexpr int DOFF[5] = {50000, 150000, 190000, 242000, 282000};
    int r, d;
    if      (i < 50000)  { r = 0; d = i; }
    else if (i < 70000)  { r = 1; d = i - 50000; }
    else if (i < 120000) { r = 2; d = i - 70000; }
    else if (i < 140000) { r = 3; d = i - 120000; }
    else                 { r = 4; d = i - 140000; }
    int nd = NDT[r];
    int* p = a.partial + PB[r] + d;
    int run = 0;
#pragma unroll
    for (int c = 0; c < 16; ++c) {
      int v = p[(size_t)c * nd];
      p[(size_t)c * nd] = run;
      run += v;
    }
    a.cnt[DOFF[r] + d] = run;
    a.rs[DOFF[r] + d] = rsqrtf((float)(run > 1 ? run : 1));
  } else {
    int i = (bx - 555) * 256 + t;
    if (i >= 142000) return;
    constexpr int NST[5] = {50000, 50000, 20000, 2000, 20000};
    constexpr int PB[5]  = {2272000, 3072000, 3872000, 4192000, 4224000};
    constexpr int OOFF[5] = {0, 100000, 170000, 240000, 262000};
    int r, s;
    if      (i < 50000)  { r = 0; s = i; }
    else if (i < 100000) { r = 1; s = i - 50000; }
    else if (i < 120000) { r = 2; s = i - 100000; }
    else if (i < 122000) { r = 3; s = i - 120000; }
    else                 { r = 4; s = i - 122000; }
    int ns = NST[r];
    const int* p = a.partial + PB[r] + s;
    int sum = 0;
#pragma unroll
    for (int c = 0; c < 16; ++c) sum += p[(size_t)c * ns];
    a.rs[OOFF[r] + s] = rsqrtf((float)(sum > 1 ? sum : 1));
  }
}

// ---------------- scan3: rp from cnt (self-contained prior-chunk prefix) ----------------

struct S3Args { const int* cnt; int* rp; };

__global__ __launch_bounds__(256) void k_scan3(S3Args a) {
  constexpr int CSTART[6] = {0, 49, 69, 118, 138, 140};
  constexpr int NDT[5] = {50000, 20000, 50000, 20000, 2000};
  constexpr int DOFF[5] = {50000, 150000, 190000, 242000, 282000};
  constexpr int RPOFF[5] = {0, 50001, 70002, 120003, 140004};
  int bx = blockIdx.x, r = 0;
  while (bx >= CSTART[r + 1]) ++r;
  int chunk = bx - CSTART[r];
  int nch = CSTART[r + 1] - CSTART[r];
  int n = NDT[r];
  const int* cnt = a.cnt + DOFF[r];
  int* rp = a.rp + RPOFF[r];
  int t = threadIdx.x;
  __shared__ int sd[256];
  __shared__ int choff_sh;
  int lim = chunk * 1024;
  int pre = 0;
  for (int j = t; j < lim; j += 256) pre += cnt[j];
  sd[t] = pre;
  __syncthreads();
  for (int off = 128; off > 0; off >>= 1) {
    if (t < off) sd[t] += sd[t + off];
    __syncthreads();
  }
  if (t == 0) choff_sh = sd[0];
  __syncthreads();
  int idx0 = lim + t * 4;
  int v[4];
#pragma unroll
  for (int j = 0; j < 4; ++j) v[j] = (idx0 + j < n) ? cnt[idx0 + j] : 0;
  int tsum = v[0] + v[1] + v[2] + v[3];
  sd[t] = tsum;
  __syncthreads();
  for (int s = 1; s < 256; s <<= 1) {
    int add = (t >= s) ? sd[t - s] : 0;
    __syncthreads();
    sd[t] += add;
    __syncthreads();
  }
  int off = choff_sh + sd[t] - tsum;
#pragma unroll
  for (int j = 0; j < 4; ++j) {
    if (idx0 + j < n) rp[idx0 + j] = off;
    off += v[j];
  }
  if (chunk == nch - 1 && t == 255) rp[n] = choff_sh + sd[255];
}

// ---------------- phase C: atomic-free CSR scatter ----------------
// slot = rp[d] + chunkbase[d][e/CS] + pos[e]

struct CArgs { const int* esrc[5]; const int* edst[5]; const int* pos;
               const int* rp; const int* partial; int* csr; };

__global__ __launch_bounds__(256) void k_buildC(CArgs a) {
  constexpr int ESTART[6] = {0, 1954, 3126, 4298, 4884, 5470};
  constexpr int NDT[5] = {50000, 20000, 50000, 20000, 2000};
  constexpr int CS[5]  = {31250, 18750, 18750, 9375, 9375};
  constexpr int EE[5]  = {500000, 300000, 300000, 150000, 150000};
  constexpr int PB[5]  = {0, 800000, 1120000, 1920000, 2240000};
  constexpr int RPOFF[5] = {0, 50001, 70002, 120003, 140004};
  constexpr int COFF[5] = {0, 500000, 800000, 1100000, 1250000};
  int bx = blockIdx.x, r = 0;
  while (bx >= ESTART[r + 1]) ++r;
  int i = (bx - ESTART[r]) * 256 + threadIdx.x;
  if (i < EE[r]) {
    int d = a.edst[r][i];
    int c = i / CS[r];
    int slot = a.rp[RPOFF[r] + d] + a.partial[PB[r] + (size_t)c * NDT[r] + d]
             + a.pos[COFF[r] + i];
    a.csr[COFF[r] + slot] = a.esrc[r][i];
  }
}

// ---------------- shared gather inner loop ----------------

#define GROW(vv, cc)                                                              \
  _Pragma("unroll") for (int q = 0; q < 8; ++q)                                   \
      acc[q] = fmaf(__uint_as_float(((unsigned)(unsigned short)vv[q]) << 16), cc, acc[q]);

__device__ __forceinline__ void gat_accum(const int* __restrict__ rp,
    const int* __restrict__ csr, const unsigned short* __restrict__ Y,
    const float* __restrict__ rso, int wid, int sub, float* acc) {
  int e0 = rp[wid], e1 = rp[wid + 1];
  for (int base = e0; base < e1; base += 16) {
    int m = e1 - base;
    if (m > 16) m = 16;
    int ei = base + (sub < m ? sub : 0);
    int se = csr[ei];
    float sc = rso[se];
    if (m == 16) {
      bf16x8 v[16];
#pragma unroll
      for (int j = 0; j < 16; ++j) {
        int sj = __shfl(se, j, 16);
        v[j] = *(const bf16x8*)&Y[(size_t)sj * 128 + sub * 8];
      }
#pragma unroll
      for (int j = 0; j < 16; ++j) {
        float cj = __shfl(sc, j, 16);
        GROW(v[j], cj)
      }
    } else {
      int j = 0;
      for (; j + 8 <= m; j += 8) {
        int s0 = __shfl(se, j, 16), s1 = __shfl(se, j + 1, 16);
        int s2 = __shfl(se, j + 2, 16), s3 = __shfl(se, j + 3, 16);
        int s4 = __shfl(se, j + 4, 16), s5 = __shfl(se, j + 5, 16);
        int s6 = __shfl(se, j + 6, 16), s7 = __shfl(se, j + 7, 16);
        float c0 = __shfl(sc, j, 16), c1 = __shfl(sc, j + 1, 16);
        float c2 = __shfl(sc, j + 2, 16), c3 = __shfl(sc, j + 3, 16);
        float c4 = __shfl(sc, j + 4, 16), c5 = __shfl(sc, j + 5, 16);
        float c6 = __shfl(sc, j + 6, 16), c7 = __shfl(sc, j + 7, 16);
        bf16x8 v0 = *(const bf16x8*)&Y[(size_t)s0 * 128 + sub * 8];
        bf16x8 v1 = *(const bf16x8*)&Y[(size_t)s1 * 128 + sub * 8];
        bf16x8 v2 = *(const bf16x8*)&Y[(size_t)s2 * 128 + sub * 8];
        bf16x8 v3 = *(const bf16x8*)&Y[(size_t)s3 * 128 + sub * 8];
        bf16x8 v4 = *(const bf16x8*)&Y[(size_t)s4 * 128 + sub * 8];
        bf16x8 v5 = *(const bf16x8*)&Y[(size_t)s5 * 128 + sub * 8];
        bf16x8 v6 = *(const bf16x8*)&Y[(size_t)s6 * 128 + sub * 8];
        bf16x8 v7 = *(const bf16x8*)&Y[(size_t)s7 * 128 + sub * 8];
        GROW(v0, c0) GROW(v1, c1) GROW(v2, c2) GROW(v3, c3)
        GROW(v4, c4) GROW(v5, c5) GROW(v6, c6) GROW(v7, c7)
      }
      for (; j < m; ++j) {
        int s0 = __shfl(se, j, 16);
        float c0 = __shfl(sc, j, 16);
        bf16x8 v0 = *(const bf16x8*)&Y[(size_t)s0 * 128 + sub * 8];
        GROW(v0, c0)
      }
    }
  }
}

// ---------------- layer-1 gather: Y -> h1 (bias + mean + lrelu fused) ----------------

struct G1Rel { const int* rp; const int* csr; const unsigned short* Y;
               const float* rso; const float* rsi; };
struct G1Args { G1Rel rel[5]; const float* b;
                unsigned short* hU; unsigned short* hN; unsigned short* hS; };

__global__ __launch_bounds__(256) void k_gather1(G1Args a) {
  int bx = blockIdx.x;
  int t = threadIdx.x;
  int sub = t & 15;
  float acc[8], tot[8];
#pragma unroll
  for (int q = 0; q < 8; ++q) acc[q] = 0.f;
  if (bx < 3125) {  // users: rel 0 + rel 2
    int wid = bx * 16 + (t >> 4);
    gat_accum(a.rel[0].rp, a.rel[0].csr, a.rel[0].Y, a.rel[0].rso, wid, sub, acc);
    float s0 = a.rel[0].rsi[wid];
#pragma unroll
    for (int q = 0; q < 8; ++q) { tot[q] = s0 * acc[q]; acc[q] = 0.f; }
    gat_accum(a.rel[2].rp, a.rel[2].csr, a.rel[2].Y, a.rel[2].rso, wid, sub, acc);
    float s2 = a.rel[2].rsi[wid];
    const float* b0 = a.b;
    const float* b2 = a.b + 2 * 128;
    u16x8 o;
#pragma unroll
    for (int q = 0; q < 8; ++q) {
      float v = 0.5f * (tot[q] + s2 * acc[q] + b0[sub * 8 + q] + b2[sub * 8 + q]);
      v = v >= 0.f ? v : LRELU * v;
      o[q] = f2bf(v);
    }
    *(u16x8*)&a.hU[(size_t)wid * 128 + sub * 8] = o;
  } else if (bx < 4375) {  // news: rel 1 + rel 3
    int wid = (bx - 3125) * 16 + (t >> 4);
    gat_accum(a.rel[1].rp, a.rel[1].csr, a.rel[1].Y, a.rel[1].rso, wid, sub, acc);
    float s1 = a.rel[1].rsi[wid];
#pragma unroll
    for (int q = 0; q < 8; ++q) { tot[q] = s1 * acc[q]; acc[q] = 0.f; }
    gat_accum(a.rel[3].rp, a.rel[3].csr, a.rel[3].Y, a.rel[3].rso, wid, sub, acc);
    float s3 = a.rel[3].rsi[wid];
    const float* b1v = a.b + 128;
    const float* b3 = a.b + 3 * 128;
    u16x8 o;
#pragma unroll
    for (int q = 0; q < 8; ++q) {
      float v = 0.5f * (tot[q] + s3 * acc[q] + b1v[sub * 8 + q] + b3[sub * 8 + q]);
      v = v >= 0.f ? v : LRELU * v;
      o[q] = f2bf(v);
    }
    *(u16x8*)&a.hN[(size_t)wid * 128 + sub * 8] = o;
  } else {  // sources: rel 4
    int wid = (bx - 4375) * 16 + (t >> 4);
    gat_accum(a.rel[4].rp, a.rel[4].csr, a.rel[4].Y, a.rel[4].rso, wid, sub, acc);
    float s4 = a.rel[4].rsi[wid];
    const float* b4 = a.b + 4 * 128;
    u16x8 o;
#pragma unroll
    for (int q = 0; q < 8; ++q) {
      float v = s4 * acc[q] + b4[sub * 8 + q];
      v = v >= 0.f ? v : LRELU * v;
      o[q] = f2bf(v);
    }
    *(u16x8*)&a.hS[(size_t)wid * 128 + sub * 8] = o;
  }
}

// ---------------- layer-2 gather (h1 -> agg, bf16) ----------------

struct RelG {
  const int* rp; const int* csr; const unsigned short* xb;
  const float* rso; const float* rsi;
  unsigned short* out; int stride; int ooff; int nd;
};
struct GArgs { RelG rel[5]; };

__global__ __launch_bounds__(256) void k_gather(GArgs a) {
  constexpr int GSTART[6] = {0, 3125, 4375, 7500, 8750, 8875};
  int bx = blockIdx.x, r = 0;
  while (bx >= GSTART[r + 1]) ++r;
  RelG g = a.rel[r];
  int t = threadIdx.x;
  int sub = t & 15;
  int wid = (bx - GSTART[r]) * 16 + (t >> 4);
  if (wid >= g.nd) return;
  float acc[8];
#pragma unroll
  for (int q = 0; q < 8; ++q) acc[q] = 0.f;
  gat_accum(g.rp, g.csr, g.xb, g.rso, wid, sub, acc);
  float si = g.rsi[wid];
  u16x8 o;
#pragma unroll
  for (int q = 0; q < 8; ++q) o[q] = f2bf(acc[q] * si);
  *(u16x8*)&g.out[(size_t)wid * g.stride + g.ooff + sub * 8] = o;
}

// ---------------- MFMA GEMM (fused 3 dst-types per launch) ----------------

struct MJob { const unsigned short* A; const unsigned short* Wh; const unsigned short* Wl;
              const float* b0; const float* b1; float scale; int lrelu;
              float* H; int ldh; unsigned short* Hb; int M; int bstart; };
struct MArgs { MJob j[3]; };

template <int KCH, int NW>
__device__ __forceinline__ void mgemm_body(const MJob& p, int bxl) {
  constexpr int KP = KCH * 128;
  int t = threadIdx.x;
  int w = t >> 6, l = t & 63;
  int lo16 = l & 15, hi4 = l >> 4;
  int m0 = bxl * 64;
  int M = p.M;
  const unsigned short* A = p.A;
  f32x4 acc[4][NW] = {};
  for (int s = 0; s < KP / 32; ++s) {
    int kbase = s * 32 + hi4 * 8;
    bf16x8 af[4];
#pragma unroll
    for (int mf = 0; mf < 4; ++mf) {
      int row = m0 + mf * 16 + lo16;
      row = row < M ? row : M - 1;  // clamp; OOB rows never stored
      af[mf] = *(const bf16x8*)&A[(size_t)row * KP + kbase];
    }
#pragma unroll
    for (int nf = 0; nf < NW; ++nf) {
      int n = (w * NW + nf) * 16 + lo16;
      bf16x8 bh = *(const bf16x8*)&p.Wh[(size_t)n * KP + kbase];
      bf16x8 bl = *(const bf16x8*)&p.Wl[(size_t)n * KP + kbase];
#pragma unroll
      for (int mf = 0; mf < 4; ++mf) {
        acc[mf][nf] = __builtin_amdgcn_mfma_f32_16x16x32_bf16(af[mf], bh, acc[mf][nf], 0, 0, 0);
        acc[mf][nf] = __builtin_amdgcn_mfma_f32_16x16x32_bf16(af[mf], bl, acc[mf][nf], 0, 0, 0);
      }
    }
  }
#pragma unroll
  for (int nf = 0; nf < NW; ++nf) {
    int col = (w * NW + nf) * 16 + lo16;
    float bs = p.b0[col];
    if (p.b1) bs += p.b1[col];
#pragma unroll
    for (int mf = 0; mf < 4; ++mf) {
#pragma unroll
      for (int rr = 0; rr < 4; ++rr) {
        int row = m0 + mf * 16 + hi4 * 4 + rr;
        if (row < M) {
          float o = p.scale * (acc[mf][nf][rr] + bs);
          if (p.lrelu) o = o >= 0.f ? o : LRELU * o;
          if (p.H) p.H[(size_t)row * p.ldh + col] = o;
          if (p.Hb) p.Hb[(size_t)row * p.ldh + col] = f2bf(o);
        }
      }
    }
  }
}

__global__ __launch_bounds__(256) void k_mgemm3(MArgs a) {
  int bx = blockIdx.x;
  if (bx < a.j[1].bstart)      mgemm_body<2, 2>(a.j[0], bx);
  else if (bx < a.j[2].bstart) mgemm_body<2, 2>(a.j[1], bx - a.j[1].bstart);
  else                         mgemm_body<1, 2>(a.j[2], bx - a.j[2].bstart);
}

__global__ __launch_bounds__(256) void k_proj3(MArgs a) {
  int bx = blockIdx.x;
  if (bx < a.j[1].bstart)      mgemm_body<1, 1>(a.j[0], bx);
  else if (bx < a.j[2].bstart) mgemm_body<1, 1>(a.j[1], bx - a.j[1].bstart);
  else                         mgemm_body<1, 1>(a.j[2], bx - a.j[2].bstart);
}

// ---------------- host ----------------

extern "C" void kernel_launch(void* const* d_in, const int* in_sizes, int n_in,
                              void* d_out, int out_size, void* d_ws, size_t ws_size,
                              hipStream_t stream) {
  const float* xu = (const float*)d_in[0];
  const float* xn = (const float*)d_in[1];
  const float* xs = (const float*)d_in[2];
  const float* W1 = (const float*)d_in[3];
  const float* b1 = (const float*)d_in[4];
  const float* W2 = (const float*)d_in[5];
  const float* b2 = (const float*)d_in[6];
  const float* Wu = (const float*)d_in[7];
  const float* bu = (const float*)d_in[8];
  const float* Wn = (const float*)d_in[9];
  const float* bn = (const float*)d_in[10];
  const float* Wsrc = (const float*)d_in[11];
  const float* bsrc = (const float*)d_in[12];
  const int* SRC[5] = {(const int*)d_in[13], (const int*)d_in[15], (const int*)d_in[17],
                       (const int*)d_in[19], (const int*)d_in[21]};
  const int* DST[5] = {(const int*)d_in[14], (const int*)d_in[16], (const int*)d_in[18],
                       (const int*)d_in[20], (const int*)d_in[22]};

  // ---- workspace layout (~69.6 MB) ----
  int* ws_i = (int*)d_ws;
  int* rp = ws_i;                           // 142008
  int* csr = ws_i + 142008;                 // 1400000
  int* pos = ws_i + 1542008;                // 1400000
  int* cnt = ws_i + 2942328;                // 284000 (din slots used)
  float* rs = (float*)(ws_i + 3226328);     // 284000
  unsigned short* wt = (unsigned short*)(rs + 284000);    // 376832
  unsigned short* aggU = wt + 376832;       // 50000*256
  unsigned short* aggN = aggU + 12800000;   // 20000*256
  unsigned short* aggS = aggN + 5120000;    // 2000*128
  unsigned short* xbU = aggS + 256000;      // 50000*128 (h1 then h2, bf16)
  unsigned short* xbN = xbU + 6400000;      // 20000*128
  unsigned short* xbS = xbN + 2560000;      // 2000*128

  // wt sub-offsets (hi, lo consecutive)
  unsigned short* L2U_h = wt + 163840, * L2U_l = wt + 196608;
  unsigned short* L2N_h = wt + 229376, * L2N_l = wt + 262144;
  unsigned short* L2S_h = wt + 294912, * L2S_l = wt + 311296;
  unsigned short* PU_h = wt + 327680, * PU_l = wt + 335872;
  unsigned short* PN_h = wt + 344064, * PN_l = wt + 352256;
  unsigned short* PS_h = wt + 360448, * PS_l = wt + 368640;

  // ---- d_out layout ----
  float* outf = (float*)d_out;
  float* ou = outf;                 // 50000*64
  float* on = outf + 3200000;       // 20000*64
  float* osrc = outf + 4480000;     // 2000*64
  float* hu = outf + 4608000;       // 50000*128
  float* hn = outf + 11008000;      // 20000*128
  float* hs = outf + 13568000;      // 2000*128

  // histogram partials / chunk-bases: 4.544M ints in the contiguous
  // ou+on+osrc region (4.608M floats) -- dead until k_proj3.
  int* partial = (int*)outf;

  // layer-1 transform outputs Y_r (bf16) in the hu/hn/hs region;
  // consumed by k_gather1, dead before layer-2 mgemm3 overwrites.
  unsigned short* Yb = (unsigned short*)(outf + 4608000);
  unsigned short* Y0 = Yb;              // 50000*128 (follows, src U)
  unsigned short* Y1 = Y0 + 6400000;    // 50000*128 (posts, src U)
  unsigned short* Y2 = Y1 + 6400000;    // 20000*128 (posted_by, src N)
  unsigned short* Y3 = Y2 + 2560000;    // 2000*128  (publishes, src S)
  unsigned short* Y4 = Y3 + 256000;     // 20000*128 (published_by, src N)

  // ---- phase A: hists (din rank + dout) + transform + wprep, no memset ----
  AArgs aa;
  for (int r = 0; r < 5; ++r) { aa.esrc[r] = SRC[r]; aa.edst[r] = DST[r]; }
  aa.pos = pos;
  aa.partial = partial;
  aa.tj[0] = {xu, W1 + 0 * 16384, Y0, kNU};
  aa.tj[1] = {xu, W1 + 1 * 16384, Y1, kNU};
  aa.tj[2] = {xn, W1 + 2 * 16384, Y2, kNN};
  aa.tj[3] = {xs, W1 + 3 * 16384, Y3, kNS};
  aa.tj[4] = {xn, W1 + 4 * 16384, Y4, kNN};
  aa.pj[0] = {W2, W2 + 2 * 16384, L2U_h, L2U_l, 128, 8, 0};
  aa.pj[1] = {W2 + 16384, W2 + 3 * 16384, L2N_h, L2N_l, 128, 8, 128};
  aa.pj[2] = {W2 + 4 * 16384, nullptr, L2S_h, L2S_l, 128, 7, 256};
  aa.pj[3] = {Wu, nullptr, PU_h, PU_l, 64, 7, 320};
  aa.pj[4] = {Wn, nullptr, PN_h, PN_l, 64, 7, 352};
  aa.pj[5] = {Wsrc, nullptr, PS_h, PS_l, 64, 7, 384};
  k_histA<<<3310, 256, 0, stream>>>(aa);

  // ---- phase B: chunk prefixes + rs + cnt ----
  BArgs ba = {partial, cnt, rs};
  k_scanB<<<1110, 256, 0, stream>>>(ba);

  // ---- rp scan ----
  S3Args s3 = {cnt, rp};
  k_scan3<<<140, 256, 0, stream>>>(s3);

  // ---- phase C: CSR scatter ----
  CArgs ca;
  for (int r = 0; r < 5; ++r) { ca.esrc[r] = SRC[r]; ca.edst[r] = DST[r]; }
  ca.pos = pos;
  ca.rp = rp;
  ca.partial = partial;
  ca.csr = csr;
  k_buildC<<<5470, 256, 0, stream>>>(ca);

  // ---- layer 1: gather Y -> h1 (bf16 into xb*, fused bias/mean/lrelu) ----
  G1Args g1;
  const unsigned short* YT[5] = {Y0, Y1, Y2, Y3, Y4};
  for (int r = 0; r < 5; ++r)
    g1.rel[r] = {rp + RP_OFF[r], csr + CSR_OFF[r], YT[r],
                 rs + DOUT_OFF[r], rs + DIN_OFF[r]};
  g1.b = b1;
  g1.hU = xbU; g1.hN = xbN; g1.hS = xbS;
  k_gather1<<<4500, 256, 0, stream>>>(g1);

  // ---- layer 2: gather h1 -> agg, then fused MFMA GEMM -> h2 ----
  {
    const unsigned short* XIN[5] = {xbU, xbU, xbN, xbS, xbN};
    unsigned short* OUT[5] = {aggU, aggN, aggU, aggN, aggS};
    const int OSTR[5] = {256, 256, 256, 256, 128};
    const int OOFF[5] = {0, 0, 128, 128, 0};
    GArgs ga;
    for (int r = 0; r < 5; ++r)
      ga.rel[r] = {rp + RP_OFF[r], csr + CSR_OFF[r], XIN[r], rs + DOUT_OFF[r],
                   rs + DIN_OFF[r], OUT[r], OSTR[r], OOFF[r],
                   (r == 0 || r == 2) ? kNU : (r == 4 ? kNS : kNN)};
    k_gather<<<8875, 256, 0, stream>>>(ga);
    MArgs ma;
    ma.j[0] = {aggU, L2U_h, L2U_l, b2, b2 + 2 * 128, 0.5f, 1, hu, 128, xbU, kNU, 0};
    ma.j[1] = {aggN, L2N_h, L2N_l, b2 + 128, b2 + 3 * 128, 0.5f, 1, hn, 128, xbN, kNN, 782};
    ma.j[2] = {aggS, L2S_h, L2S_l, b2 + 4 * 128, nullptr, 1.0f, 1, hs, 128, xbS, kNS, 1095};
    k_mgemm3<<<1127, 256, 0, stream>>>(ma);
  }

  // ---- output projections (read bf16 h2 from xb*) ----
  MArgs pm;
  pm.j[0] = {xbU, PU_h, PU_l, bu, nullptr, 1.0f, 0, ou, 64, nullptr, kNU, 0};
  pm.j[1] = {xbN, PN_h, PN_l, bn, nullptr, 1.0f, 0, on, 64, nullptr, kNN, 782};
  pm.j[2] = {xbS, PS_h, PS_l, bsrc, nullptr, 1.0f, 0, osrc, 64, nullptr, kNS, 1095};
  k_proj3<<<1127, 256, 0, stream>>>(pm);
}